// Round 11
// baseline (146.401 us; speedup 1.0000x reference)
//
#include <hip/hip_runtime.h>

#define B_ 8
#define N_ 4096
#define F_ 512

typedef __attribute__((ext_vector_type(8))) short bf16x8;
typedef __attribute__((ext_vector_type(4))) float f32x4;

// S (512 x 64) = [left | right | left_local | right_local], each [512][16] row-major.
__device__ __forceinline__ float Sval(const float* l, const float* r,
                                      const float* ll, const float* rl,
                                      int h, int e) {
    const int m = e >> 4, c = e & 15;
    const float* p = (m == 0) ? l : (m == 1) ? r : (m == 2) ? ll : rl;
    return p[h * 16 + c];
}

__device__ __forceinline__ float qval(const float* coeff, const float* coeff_l,
                                      int b, int j) {
    if (j < 16) return 1.f;
    if (j < 32) return coeff[b * 16 + (j - 16)];
    if (j < 48) return 1.f;
    return coeff_l[b * 16 + (j - 48)];
}

__device__ __forceinline__ float lane_bcast(float v, int lane) {
    return __int_as_float(__builtin_amdgcn_readlane(__float_as_int(v), lane));
}

__device__ __forceinline__ unsigned short bf16_rn(float x) {
    unsigned u = __float_as_uint(x);
    unsigned r = u + 0x7FFFu + ((u >> 16) & 1u);
    return (unsigned short)(r >> 16);
}

// split x ~= hi + lo, both bf16 (error ~2^-17 |x|)
__device__ __forceinline__ void bf16_split(float x, short& hi, short& lo) {
    const unsigned short h = bf16_rn(x);
    const float hf = __uint_as_float(((unsigned)h) << 16);
    const unsigned short s = bf16_rn(x - hf);
    hi = (short)h; lo = (short)s;
}

// ---- k_prep: GS row i + S-fragment f2=i for phase-2 B-operand. grid 64.
__global__ __launch_bounds__(256) void k_prep(const float* l, const float* r,
                                              const float* ll, const float* rl,
                                              float* GS, unsigned short* Sf) {
    __shared__ float red[4][64];
    const int i = blockIdx.x;
    const int t = threadIdx.x;
    const int j = t & 63, seg = t >> 6;

    {
        const int ht = i >> 1, eh = i & 1;
        for (int idx = t; idx < 512; idx += 256) {
            const int lx = idx >> 3, ii = idx & 7;
            const int h = ht * 16 + (lx & 15);
            const int e = eh * 32 + ((lx >> 4) & 3) * 8 + ii;
            short hh, ss;
            bf16_split(Sval(l, r, ll, rl, h, e), hh, ss);
            Sf[(i * 2 + 0) * 512 + idx] = (unsigned short)hh;
            Sf[(i * 2 + 1) * 512 + idx] = (unsigned short)ss;
        }
    }

    float acc = 0.f;
    const int h0 = seg * 128;
    for (int h = h0; h < h0 + 128; ++h)
        acc += Sval(l, r, ll, rl, h, i) * Sval(l, r, ll, rl, h, j);
    red[seg][j] = acc;
    __syncthreads();
    if (t < 64) GS[i * 64 + t] = red[0][t] + red[1][t] + red[2][t] + red[3][t];
}

// ---- k_pre: build CP and M = I - 0.5 CQ^T GS CP -> Mws, CPws. 8 blocks.
__global__ __launch_bounds__(256) void k_pre(const float* coeff, const float* gate,
                                             const float* coeff_l, const float* gate_l,
                                             const float* comm, const float* GS,
                                             float* Mws, float* CPws) {
    __shared__ float GST[4096];
    __shared__ float CPs[4096];
    __shared__ float ABs[2048];
    __shared__ float u1s[32], u2s[32];

    const int b = blockIdx.x, t = threadIdx.x;
    const int tx = t & 15, ty = t >> 4;
    const float g = gate[b], gl = gate_l[b];
    const float cs = comm[b] / 12.0f;

    if (t < 32) {
        u1s[t] = (t < 16) ? g * coeff[b * 16 + t] : -g;
        u2s[t] = (t < 16) ? gl * coeff_l[b * 16 + t] : -gl;
    }
    for (int idx = t; idx < 4096; idx += 256) {
        const int i = idx & 63, e = idx >> 6;
        GST[idx] = -0.5f * qval(coeff, coeff_l, b, i) * GS[(i ^ 16) * 64 + e];
    }
    __syncthreads();

    for (int idx = t; idx < 2048; idx += 256) {
        const int which = idx >> 10;
        const int i = (idx >> 5) & 31, j = idx & 31;
        float val;
        if (which == 0) {
            const int v2i = (i < 16) ? 48 + i : 16 + i;
            const float v2sc = (i < 16) ? 1.f : coeff_l[b * 16 + (i - 16)];
            val = v2sc * u1s[j] * GS[v2i * 64 + j];
        } else {
            const int v1i = (i < 16) ? 16 + i : i - 16;
            const float v1sc = (i < 16) ? 1.f : coeff[b * 16 + (i - 16)];
            val = v1sc * u2s[j] * GS[v1i * 64 + 32 + j];
        }
        ABs[idx] = val;
    }
    __syncthreads();

    for (int idx = t; idx < 4096; idx += 256) {
        const int e = idx >> 6, j = idx & 63;
        float val = 0.f;
        if (j < 32) {
            if (e == j) val += 0.5f * u1s[j];
            if (e >= 32) val += cs * u2s[e - 32] * ABs[(e - 32) * 32 + j];
        } else {
            const int jp = j - 32;
            if (e == 32 + jp) val += 0.5f * u2s[jp];
            if (e < 32) val -= cs * u1s[e] * ABs[1024 + e * 32 + jp];
        }
        CPs[idx] = val;
        CPws[b * 4096 + idx] = val;
    }
    __syncthreads();

    {
        const int i0 = ty * 4, m0 = tx * 4;
        float acc[4][4];
#pragma unroll
        for (int i = 0; i < 4; ++i)
#pragma unroll
            for (int j = 0; j < 4; ++j) acc[i][j] = 0.f;
        for (int e = 0; e < 64; ++e) {
            const float4 av = *reinterpret_cast<const float4*>(&GST[e * 64 + i0]);
            const float4 bv = *reinterpret_cast<const float4*>(&CPs[e * 64 + m0]);
            const float a[4] = {av.x, av.y, av.z, av.w};
            const float bb[4] = {bv.x, bv.y, bv.z, bv.w};
#pragma unroll
            for (int i = 0; i < 4; ++i)
#pragma unroll
                for (int j = 0; j < 4; ++j) acc[i][j] += a[i] * bb[j];
        }
#pragma unroll
        for (int i = 0; i < 4; ++i) {
            float4 o;
            o.x = acc[i][0] + (((i0 + i) == (m0 + 0)) ? 1.f : 0.f);
            o.y = acc[i][1] + (((i0 + i) == (m0 + 1)) ? 1.f : 0.f);
            o.z = acc[i][2] + (((i0 + i) == (m0 + 2)) ? 1.f : 0.f);
            o.w = acc[i][3] + (((i0 + i) == (m0 + 3)) ? 1.f : 0.f);
            *reinterpret_cast<float4*>(&Mws[b * 4096 + (i0 + i) * 64 + m0]) = o;
        }
    }
}

// ---- k_inv: 4-wave register Gauss-Jordan. Wave w owns rows 16w..16w+15
// (a[16], static indices only — rule #20). Lane = column. Pivot row (as akp =
// normalized row + onehot(K)) is broadcast via parity-double-buffered LDS with
// ONE barrier/step: reads of P[p] at step K complete before barrier(K); the
// next write of P[p] (step K+2... i.e. K+1's buffer is the other parity) occurs
// after barrier(K) — ordered. Replaces the single-wave version whose 8k serial
// readlane->SGPR->fma pairs cost ~50us (hidden under top-5 cutoff R4-R10).
__global__ __launch_bounds__(256, 1) void k_inv(const float* Mws, float* Kws) {
    __shared__ float P[2][64];
    const int b = blockIdx.x;
    const int t = threadIdx.x;
    const int w = t >> 6, l = t & 63;
    const int base = b * 4096;
    float a[16];
#pragma unroll
    for (int i = 0; i < 16; ++i) a[i] = Mws[base + (w * 16 + i) * 64 + l];

    for (int K = 0; K < 64; ++K) {
        if ((K >> 4) == w) {
#pragma unroll
            for (int i = 0; i < 16; ++i) {
                if ((w * 16 + i) == K) {
                    const float dk = lane_bcast(a[i], K);
                    const float pinv = 1.0f / dk;
                    a[i] = (l == K) ? pinv : a[i] * pinv;
                    P[K & 1][l] = a[i] + ((l == K) ? 1.0f : 0.0f);
                }
            }
        }
        __syncthreads();
        const float pv = P[K & 1][l];
#pragma unroll
        for (int i = 0; i < 16; ++i) {
            if ((w * 16 + i) != K) {
                const float f = lane_bcast(a[i], K);
                a[i] = __builtin_fmaf(-f, pv, a[i]);
            }
        }
    }
#pragma unroll
    for (int i = 0; i < 16; ++i) Kws[base + (w * 16 + i) * 64 + l] = a[i];
}

// ---- k_post: Newton refinement + E. 8 blocks.
__global__ __launch_bounds__(256) void k_post(const float* coeff, const float* coeff_l,
                                              const float* Mws, const float* CPws,
                                              const float* Kws, float* Eout) {
    __shared__ float Ms[4096], CPs[4096], Ks[4096], Tds[4096], Tas[4096];
    const int b = blockIdx.x, t = threadIdx.x;
    const int tx = t & 15, ty = t >> 4;

    for (int idx = t; idx < 4096; idx += 256) {
        Ms[idx] = Mws[b * 4096 + idx];
        CPs[idx] = CPws[b * 4096 + idx];
        Ks[idx] = Kws[b * 4096 + idx];
    }
    __syncthreads();

    {
        const int i0 = ty * 4, j0 = tx * 4;
        float accd[4][4], acca[4][4];
#pragma unroll
        for (int i = 0; i < 4; ++i)
#pragma unroll
            for (int j = 0; j < 4; ++j) { accd[i][j] = 0.f; acca[i][j] = 0.f; }
        for (int q = 0; q < 64; ++q) {
            const float4 bv = *reinterpret_cast<const float4*>(&Ks[q * 64 + j0]);
            const float bb[4] = {bv.x, bv.y, bv.z, bv.w};
            float ad[4], aa[4];
#pragma unroll
            for (int i = 0; i < 4; ++i) {
                ad[i] = CPs[(i0 + i) * 64 + q];
                aa[i] = Ms[(i0 + i) * 64 + q];
            }
#pragma unroll
            for (int i = 0; i < 4; ++i)
#pragma unroll
                for (int j = 0; j < 4; ++j) {
                    accd[i][j] += ad[i] * bb[j];
                    acca[i][j] += aa[i] * bb[j];
                }
        }
#pragma unroll
        for (int i = 0; i < 4; ++i)
#pragma unroll
            for (int j = 0; j < 4; ++j) {
                Tds[(i0 + i) * 64 + j0 + j] = accd[i][j];
                Tas[(i0 + i) * 64 + j0 + j] = acca[i][j];
            }
    }
    __syncthreads();

    {
        const int e0 = ty * 4, c0 = tx * 4;
        float acc[4][4];
#pragma unroll
        for (int i = 0; i < 4; ++i)
#pragma unroll
            for (int j = 0; j < 4; ++j) acc[i][j] = 0.f;
        for (int q = 0; q < 64; ++q) {
            const float4 bv = *reinterpret_cast<const float4*>(&Tas[q * 64 + c0]);
            const float bb[4] = {bv.x, bv.y, bv.z, bv.w};
            float a[4];
#pragma unroll
            for (int i = 0; i < 4; ++i) a[i] = Tds[(e0 + i) * 64 + q];
#pragma unroll
            for (int i = 0; i < 4; ++i)
#pragma unroll
                for (int j = 0; j < 4; ++j) acc[i][j] += a[i] * bb[j];
        }
        float qv[4];
#pragma unroll
        for (int j = 0; j < 4; ++j) qv[j] = qval(coeff, coeff_l, b, c0 + j);
#pragma unroll
        for (int i = 0; i < 4; ++i) {
            float4 o;
            o.x = qv[0] * (2.f * Tds[(e0 + i) * 64 + c0 + 0] - acc[i][0]);
            o.y = qv[1] * (2.f * Tds[(e0 + i) * 64 + c0 + 1] - acc[i][1]);
            o.z = qv[2] * (2.f * Tds[(e0 + i) * 64 + c0 + 2] - acc[i][2]);
            o.w = qv[3] * (2.f * Tds[(e0 + i) * 64 + c0 + 3] - acc[i][3]);
            *reinterpret_cast<float4*>(&Eout[b * 4096 + (e0 + i) * 64 + (c0 ^ 16)]) = o;
        }
    }
}

// SE = S*E per batch, emitted in MFMA B-fragment layout (bf16 hi/lo).
// grid (hc=8, b=8)
__global__ __launch_bounds__(256) void k_se(const float* l, const float* r,
                                            const float* ll, const float* rl,
                                            const float* Ein, unsigned short* SEf) {
    __shared__ float Es[4096];
    __shared__ float Ss[64 * 66];
    __shared__ float SEs[64 * 65];
    const int b = blockIdx.y, hc = blockIdx.x, t = threadIdx.x;
    for (int idx = t; idx < 4096; idx += 256) {
        Es[idx] = Ein[b * 4096 + idx];
        const int hl_ = idx >> 6, e = idx & 63;
        Ss[hl_ * 66 + e] = Sval(l, r, ll, rl, hc * 64 + hl_, e);
    }
    __syncthreads();

    const int h = t >> 2;            // local row 0..63
    const int mg = (t & 3) * 16;
    float acc[16];
#pragma unroll
    for (int q = 0; q < 16; ++q) acc[q] = 0.f;
#pragma unroll 4
    for (int e = 0; e < 64; ++e) {
        const float s = Ss[h * 66 + e];
        const float* Er = Es + e * 64 + mg;
#pragma unroll
        for (int q = 0; q < 16; ++q) acc[q] += s * Er[q];
    }
#pragma unroll
    for (int q = 0; q < 16; ++q) SEs[h * 65 + mg + q] = acc[q];
    __syncthreads();

    unsigned short* outp = SEf + (size_t)b * 65536 + hc * 8192;
#pragma unroll
    for (int it = 0; it < 4; ++it) {
        const int widx0 = it * 2048 + t * 8;
        const int fl = widx0 >> 10;            // 0..7
        const int hl = (widx0 >> 9) & 1;
        const int lx = (widx0 >> 3) & 63;
        const int m = (fl & 3) * 16 + (lx & 15);
        const int hb = (fl >> 2) * 32 + ((lx >> 4) & 3) * 8;
        unsigned short wv[8];
#pragma unroll
        for (int i = 0; i < 8; ++i) {
            short hh, ss;
            bf16_split(SEs[(hb + i) * 65 + m], hh, ss);
            wv[i] = hl ? (unsigned short)ss : (unsigned short)hh;
        }
        uint4 pk;
        pk.x = (unsigned)wv[0] | ((unsigned)wv[1] << 16);
        pk.y = (unsigned)wv[2] | ((unsigned)wv[3] << 16);
        pk.z = (unsigned)wv[4] | ((unsigned)wv[5] << 16);
        pk.w = (unsigned)wv[6] | ((unsigned)wv[7] << 16);
        *reinterpret_cast<uint4*>(outp + widx0) = pk;
    }
}

// out = x + ((x * SE_b) * S^T) via split-bf16 MFMA, fragment-major B operands.
// EXACT R7 schedule (benched ~38us in R7's run): 32-row tiles, grid (128, 8),
// 256 thr = 4 waves (rw=row-half, cw=col-half), launch_bounds (256,4),
// #pragma unroll 2, x-load -> split -> B-load order.
__global__ __launch_bounds__(256, 4) void k_mix(const float* x,
                                                const unsigned short* SEf,
                                                const unsigned short* Sf,
                                                float* out) {
    __shared__ float Zs[32 * 68];
    const int b = blockIdx.y;
    const int r0 = blockIdx.x * 32;
    const int t = threadIdx.x;
    const int w = t >> 6;
    const int l = t & 63;
    const int lm = l & 15;
    const int lk = (l >> 4) * 8;
    const int rw = w & 1, cw = w >> 1;
    const float* xb = x + (size_t)b * N_ * F_;
    float* outb = out + (size_t)b * N_ * F_;
    const unsigned short* sef = SEf + (size_t)b * 65536;

    // ---- phase 1: Z[32][64] = X_tile * SE ----
    f32x4 ahh0 = {0.f, 0.f, 0.f, 0.f}, alh0 = ahh0, ahl0 = ahh0;
    f32x4 ahh1 = ahh0, alh1 = ahh0, ahl1 = ahh0;
    const int arow = r0 + 16 * rw + lm;
    const float* xrow = xb + (size_t)arow * F_;
#pragma unroll 2
    for (int kk = 0; kk < 16; ++kk) {
        const int k0 = kk * 32 + lk;
        const float4 xa = *reinterpret_cast<const float4*>(xrow + k0);
        const float4 xc = *reinterpret_cast<const float4*>(xrow + k0 + 4);
        const float xs[8] = {xa.x, xa.y, xa.z, xa.w, xc.x, xc.y, xc.z, xc.w};
        bf16x8 ah, al;
#pragma unroll
        for (int i = 0; i < 8; ++i) {
            short hh, ss;
            bf16_split(xs[i], hh, ss);
            ah[i] = hh; al[i] = ss;
        }
        const int o0 = (kk * 4 + 2 * cw) * 1024 + l * 8;
        const bf16x8 bh0 = *reinterpret_cast<const bf16x8*>(sef + o0);
        const bf16x8 bl0 = *reinterpret_cast<const bf16x8*>(sef + o0 + 512);
        const bf16x8 bh1 = *reinterpret_cast<const bf16x8*>(sef + o0 + 1024);
        const bf16x8 bl1 = *reinterpret_cast<const bf16x8*>(sef + o0 + 1536);
        ahh0 = __builtin_amdgcn_mfma_f32_16x16x32_bf16(ah, bh0, ahh0, 0, 0, 0);
        alh0 = __builtin_amdgcn_mfma_f32_16x16x32_bf16(al, bh0, alh0, 0, 0, 0);
        ahl0 = __builtin_amdgcn_mfma_f32_16x16x32_bf16(ah, bl0, ahl0, 0, 0, 0);
        ahh1 = __builtin_amdgcn_mfma_f32_16x16x32_bf16(ah, bh1, ahh1, 0, 0, 0);
        alh1 = __builtin_amdgcn_mfma_f32_16x16x32_bf16(al, bh1, alh1, 0, 0, 0);
        ahl1 = __builtin_amdgcn_mfma_f32_16x16x32_bf16(ah, bl1, ahl1, 0, 0, 0);
    }
#pragma unroll
    for (int r = 0; r < 4; ++r) {
        const int zr = (16 * rw + (l >> 4) * 4 + r) * 68 + 32 * cw;
        Zs[zr + lm] = ahh0[r] + alh0[r] + ahl0[r];
        Zs[zr + 16 + lm] = ahh1[r] + alh1[r] + ahl1[r];
    }
    __syncthreads();

    // ---- phase 2: out[32][512] = X + Z * S^T ----
    bf16x8 zh0, zl0, zh1, zl1;
    {
        const float* zrow = &Zs[(16 * rw + lm) * 68];
#pragma unroll
        for (int i = 0; i < 8; ++i) {
            short hh, ss;
            bf16_split(zrow[lk + i], hh, ss);
            zh0[i] = hh; zl0[i] = ss;
            bf16_split(zrow[32 + lk + i], hh, ss);
            zh1[i] = hh; zl1[i] = ss;
        }
    }
    const int orow0 = r0 + 16 * rw + (l >> 4) * 4;
#pragma unroll 2
    for (int j2 = 0; j2 < 16; ++j2) {
        const int ht = cw * 16 + j2;
        const int h0 = ht * 16 + lm;
        f32x4 ca = {0.f, 0.f, 0.f, 0.f};
        f32x4 cb;
#pragma unroll
        for (int r = 0; r < 4; ++r) cb[r] = xb[(size_t)(orow0 + r) * F_ + h0];
        const int fb = ht * 2048 + l * 8;
        const bf16x8 bh0 = *reinterpret_cast<const bf16x8*>(Sf + fb);
        const bf16x8 bl0 = *reinterpret_cast<const bf16x8*>(Sf + fb + 512);
        const bf16x8 bh1 = *reinterpret_cast<const bf16x8*>(Sf + fb + 1024);
        const bf16x8 bl1 = *reinterpret_cast<const bf16x8*>(Sf + fb + 1536);
        ca = __builtin_amdgcn_mfma_f32_16x16x32_bf16(zh0, bh0, ca, 0, 0, 0);
        ca = __builtin_amdgcn_mfma_f32_16x16x32_bf16(zl0, bh0, ca, 0, 0, 0);
        ca = __builtin_amdgcn_mfma_f32_16x16x32_bf16(zh0, bl0, ca, 0, 0, 0);
        cb = __builtin_amdgcn_mfma_f32_16x16x32_bf16(zh1, bh1, cb, 0, 0, 0);
        cb = __builtin_amdgcn_mfma_f32_16x16x32_bf16(zl1, bh1, cb, 0, 0, 0);
        cb = __builtin_amdgcn_mfma_f32_16x16x32_bf16(zh1, bl1, cb, 0, 0, 0);
#pragma unroll
        for (int r = 0; r < 4; ++r)
            outb[(size_t)(orow0 + r) * F_ + h0] = ca[r] + cb[r];
    }
}

extern "C" void kernel_launch(void* const* d_in, const int* in_sizes, int n_in,
                              void* d_out, int out_size, void* d_ws, size_t ws_size,
                              hipStream_t stream) {
    (void)in_sizes; (void)n_in; (void)out_size; (void)ws_size;
    const float* x       = (const float*)d_in[0];
    const float* coeff   = (const float*)d_in[1];
    const float* gate    = (const float*)d_in[2];
    const float* coeff_l = (const float*)d_in[3];
    const float* gate_l  = (const float*)d_in[4];
    const float* comm    = (const float*)d_in[5];
    const float* l       = (const float*)d_in[6];
    const float* r       = (const float*)d_in[7];
    const float* ll      = (const float*)d_in[8];
    const float* rl      = (const float*)d_in[9];

    char* wsb = (char*)d_ws;
    float* GS   = (float*)(wsb);                              // 4096 f       @0
    float* E    = (float*)(wsb + 16384);                      // 8*4096 f     @16K
    unsigned short* SEf = (unsigned short*)(wsb + 147456);    // 8*65536 u16  @144K (1MB)
    unsigned short* Sf  = (unsigned short*)(wsb + 1196032);   // 65536 u16    @1168K (128K)
    float* Mws  = (float*)(wsb + 1327104);                    // 8*4096 f     @1296K
    float* CPws = (float*)(wsb + 1458176);                    // 8*4096 f     @1424K
    float* Kws  = (float*)(wsb + 1589248);                    // 8*4096 f     @1552K (ends 1680K)
    float* out = (float*)d_out;

    k_prep<<<dim3(64), dim3(256), 0, stream>>>(l, r, ll, rl, GS, Sf);
    k_pre<<<dim3(8), dim3(256), 0, stream>>>(coeff, gate, coeff_l, gate_l, comm, GS,
                                             Mws, CPws);
    k_inv<<<dim3(8), dim3(256), 0, stream>>>(Mws, Kws);
    k_post<<<dim3(8), dim3(256), 0, stream>>>(coeff, coeff_l, Mws, CPws, Kws, E);
    k_se<<<dim3(8, 8), dim3(256), 0, stream>>>(l, r, ll, rl, E, SEf);
    k_mix<<<dim3(128, 8), dim3(256), 0, stream>>>(x, SEf, Sf, out);
}

// Round 12
// 115.820 us; speedup vs baseline: 1.2640x; 1.2640x over previous
//
#include <hip/hip_runtime.h>

#define B_ 8
#define N_ 4096
#define F_ 512

typedef __attribute__((ext_vector_type(8))) short bf16x8;
typedef __attribute__((ext_vector_type(4))) float f32x4;

// S (512 x 64) = [left | right | left_local | right_local], each [512][16] row-major.
__device__ __forceinline__ float Sval(const float* l, const float* r,
                                      const float* ll, const float* rl,
                                      int h, int e) {
    const int m = e >> 4, c = e & 15;
    const float* p = (m == 0) ? l : (m == 1) ? r : (m == 2) ? ll : rl;
    return p[h * 16 + c];
}

__device__ __forceinline__ float qval(const float* coeff, const float* coeff_l,
                                      int b, int j) {
    if (j < 16) return 1.f;
    if (j < 32) return coeff[b * 16 + (j - 16)];
    if (j < 48) return 1.f;
    return coeff_l[b * 16 + (j - 48)];
}

__device__ __forceinline__ float lane_bcast(float v, int lane) {
    return __int_as_float(__builtin_amdgcn_readlane(__float_as_int(v), lane));
}

__device__ __forceinline__ unsigned short bf16_rn(float x) {
    unsigned u = __float_as_uint(x);
    unsigned r = u + 0x7FFFu + ((u >> 16) & 1u);
    return (unsigned short)(r >> 16);
}

// split x ~= hi + lo, both bf16 (error ~2^-17 |x|)
__device__ __forceinline__ void bf16_split(float x, short& hi, short& lo) {
    const unsigned short h = bf16_rn(x);
    const float hf = __uint_as_float(((unsigned)h) << 16);
    const unsigned short s = bf16_rn(x - hf);
    hi = (short)h; lo = (short)s;
}

__device__ __forceinline__ void split8(const float4& xa, const float4& xc,
                                       bf16x8& ah, bf16x8& al) {
    const float xs[8] = {xa.x, xa.y, xa.z, xa.w, xc.x, xc.y, xc.z, xc.w};
#pragma unroll
    for (int i = 0; i < 8; ++i) {
        short hh, ss;
        bf16_split(xs[i], hh, ss);
        ah[i] = hh; al[i] = ss;
    }
}

// ---- k_prep: GS row i + S-fragment f2=i for phase-2 B-operand. grid 64.
__global__ __launch_bounds__(256) void k_prep(const float* l, const float* r,
                                              const float* ll, const float* rl,
                                              float* GS, unsigned short* Sf) {
    __shared__ float red[4][64];
    const int i = blockIdx.x;
    const int t = threadIdx.x;
    const int j = t & 63, seg = t >> 6;

    {
        const int ht = i >> 1, eh = i & 1;
        for (int idx = t; idx < 512; idx += 256) {
            const int lx = idx >> 3, ii = idx & 7;
            const int h = ht * 16 + (lx & 15);
            const int e = eh * 32 + ((lx >> 4) & 3) * 8 + ii;
            short hh, ss;
            bf16_split(Sval(l, r, ll, rl, h, e), hh, ss);
            Sf[(i * 2 + 0) * 512 + idx] = (unsigned short)hh;
            Sf[(i * 2 + 1) * 512 + idx] = (unsigned short)ss;
        }
    }

    float acc = 0.f;
    const int h0 = seg * 128;
    for (int h = h0; h < h0 + 128; ++h)
        acc += Sval(l, r, ll, rl, h, i) * Sval(l, r, ll, rl, h, j);
    red[seg][j] = acc;
    __syncthreads();
    if (t < 64) GS[i * 64 + t] = red[0][t] + red[1][t] + red[2][t] + red[3][t];
}

// ---- k_pre: build CP and M = I - 0.5 CQ^T GS CP -> Mws, CPws. 8 blocks.
__global__ __launch_bounds__(256) void k_pre(const float* coeff, const float* gate,
                                             const float* coeff_l, const float* gate_l,
                                             const float* comm, const float* GS,
                                             float* Mws, float* CPws) {
    __shared__ float GST[4096];
    __shared__ float CPs[4096];
    __shared__ float ABs[2048];
    __shared__ float u1s[32], u2s[32];

    const int b = blockIdx.x, t = threadIdx.x;
    const int tx = t & 15, ty = t >> 4;
    const float g = gate[b], gl = gate_l[b];
    const float cs = comm[b] / 12.0f;

    if (t < 32) {
        u1s[t] = (t < 16) ? g * coeff[b * 16 + t] : -g;
        u2s[t] = (t < 16) ? gl * coeff_l[b * 16 + t] : -gl;
    }
    for (int idx = t; idx < 4096; idx += 256) {
        const int i = idx & 63, e = idx >> 6;
        GST[idx] = -0.5f * qval(coeff, coeff_l, b, i) * GS[(i ^ 16) * 64 + e];
    }
    __syncthreads();

    for (int idx = t; idx < 2048; idx += 256) {
        const int which = idx >> 10;
        const int i = (idx >> 5) & 31, j = idx & 31;
        float val;
        if (which == 0) {
            const int v2i = (i < 16) ? 48 + i : 16 + i;
            const float v2sc = (i < 16) ? 1.f : coeff_l[b * 16 + (i - 16)];
            val = v2sc * u1s[j] * GS[v2i * 64 + j];
        } else {
            const int v1i = (i < 16) ? 16 + i : i - 16;
            const float v1sc = (i < 16) ? 1.f : coeff[b * 16 + (i - 16)];
            val = v1sc * u2s[j] * GS[v1i * 64 + 32 + j];
        }
        ABs[idx] = val;
    }
    __syncthreads();

    for (int idx = t; idx < 4096; idx += 256) {
        const int e = idx >> 6, j = idx & 63;
        float val = 0.f;
        if (j < 32) {
            if (e == j) val += 0.5f * u1s[j];
            if (e >= 32) val += cs * u2s[e - 32] * ABs[(e - 32) * 32 + j];
        } else {
            const int jp = j - 32;
            if (e == 32 + jp) val += 0.5f * u2s[jp];
            if (e < 32) val -= cs * u1s[e] * ABs[1024 + e * 32 + jp];
        }
        CPs[idx] = val;
        CPws[b * 4096 + idx] = val;
    }
    __syncthreads();

    {
        const int i0 = ty * 4, m0 = tx * 4;
        float acc[4][4];
#pragma unroll
        for (int i = 0; i < 4; ++i)
#pragma unroll
            for (int j = 0; j < 4; ++j) acc[i][j] = 0.f;
        for (int e = 0; e < 64; ++e) {
            const float4 av = *reinterpret_cast<const float4*>(&GST[e * 64 + i0]);
            const float4 bv = *reinterpret_cast<const float4*>(&CPs[e * 64 + m0]);
            const float a[4] = {av.x, av.y, av.z, av.w};
            const float bb[4] = {bv.x, bv.y, bv.z, bv.w};
#pragma unroll
            for (int i = 0; i < 4; ++i)
#pragma unroll
                for (int j = 0; j < 4; ++j) acc[i][j] += a[i] * bb[j];
        }
#pragma unroll
        for (int i = 0; i < 4; ++i) {
            float4 o;
            o.x = acc[i][0] + (((i0 + i) == (m0 + 0)) ? 1.f : 0.f);
            o.y = acc[i][1] + (((i0 + i) == (m0 + 1)) ? 1.f : 0.f);
            o.z = acc[i][2] + (((i0 + i) == (m0 + 2)) ? 1.f : 0.f);
            o.w = acc[i][3] + (((i0 + i) == (m0 + 3)) ? 1.f : 0.f);
            *reinterpret_cast<float4*>(&Mws[b * 4096 + (i0 + i) * 64 + m0]) = o;
        }
    }
}

// ---- k_inv: BLOCKED single-wave register Gauss-Jordan, 8 macro-steps, 0 barriers.
// Lane t = column, a[64] in VGPRs (64-thread launch_bounds(64,1): R4-proven no-spill).
// Macro-step G (pivot rows 8G..8G+7):
//   (1) snapshot multiplier columns: lanes 8G..8G+7 write a[r] -> Msnap[r][lane&7]
//   (2) in-panel sequential GJ on the 8 group rows (akp trick per step)
//   (3) trailing rank-8 update: a[r] -= sum_j Msnap[r][j] * akp[j]  (broadcast
//       ds_read_b128 x2 + 8 fma per row) — blockwise akp-trick gives the exact
//       in-place inverse including the -A_rG D^{-1} columns.
// Replaces 64 serial (barrier|readlane-chain) steps (58us, VALUBusy 12% on
// active CUs) with 8 steps; readlanes 4096 -> 512, barriers 64 -> 0.
#define DO64(M, K) \
    M(0, K) M(1, K) M(2, K) M(3, K) M(4, K) M(5, K) M(6, K) M(7, K) \
    M(8, K) M(9, K) M(10, K) M(11, K) M(12, K) M(13, K) M(14, K) M(15, K) \
    M(16, K) M(17, K) M(18, K) M(19, K) M(20, K) M(21, K) M(22, K) M(23, K) \
    M(24, K) M(25, K) M(26, K) M(27, K) M(28, K) M(29, K) M(30, K) M(31, K) \
    M(32, K) M(33, K) M(34, K) M(35, K) M(36, K) M(37, K) M(38, K) M(39, K) \
    M(40, K) M(41, K) M(42, K) M(43, K) M(44, K) M(45, K) M(46, K) M(47, K) \
    M(48, K) M(49, K) M(50, K) M(51, K) M(52, K) M(53, K) M(54, K) M(55, K) \
    M(56, K) M(57, K) M(58, K) M(59, K) M(60, K) M(61, K) M(62, K) M(63, K)

#define GJ_LOAD(RR, K) a[RR] = Mws[base + (RR)*64 + t];
#define GJ_STORE(RR, K) Kws[base + (RR)*64 + t] = a[RR];

#define INV_SNAP(RR, G) if (ing) Msnap[(RR) * 8 + gl] = a[RR];

#define IGU(I, G, J) \
    if ((I) != (J)) { \
        const float f_ = lane_bcast(a[(G)*8 + (I)], (G)*8 + (J)); \
        a[(G)*8 + (I)] = __builtin_fmaf(-f_, akp[J], a[(G)*8 + (I)]); \
    }

#define IGS(G, J) { \
    const float dk = lane_bcast(a[(G)*8 + (J)], (G)*8 + (J)); \
    const float pinv = 1.0f / dk; \
    a[(G)*8 + (J)] = (t == ((G)*8 + (J))) ? pinv : a[(G)*8 + (J)] * pinv; \
    akp[J] = a[(G)*8 + (J)] + ((t == ((G)*8 + (J))) ? 1.0f : 0.0f); \
    IGU(0, G, J) IGU(1, G, J) IGU(2, G, J) IGU(3, G, J) \
    IGU(4, G, J) IGU(5, G, J) IGU(6, G, J) IGU(7, G, J) }

#define TRL(RR, G) \
    if (((RR) >> 3) != (G)) { \
        const float4 m0 = *reinterpret_cast<const float4*>(&Msnap[(RR) * 8]); \
        const float4 m1 = *reinterpret_cast<const float4*>(&Msnap[(RR) * 8 + 4]); \
        a[RR] = __builtin_fmaf(-m0.x, akp[0], a[RR]); \
        a[RR] = __builtin_fmaf(-m0.y, akp[1], a[RR]); \
        a[RR] = __builtin_fmaf(-m0.z, akp[2], a[RR]); \
        a[RR] = __builtin_fmaf(-m0.w, akp[3], a[RR]); \
        a[RR] = __builtin_fmaf(-m1.x, akp[4], a[RR]); \
        a[RR] = __builtin_fmaf(-m1.y, akp[5], a[RR]); \
        a[RR] = __builtin_fmaf(-m1.z, akp[6], a[RR]); \
        a[RR] = __builtin_fmaf(-m1.w, akp[7], a[RR]); \
    }

#define MACRO_STEP(G) { \
    float akp[8]; \
    const bool ing = ((t >> 3) == (G)); \
    DO64(INV_SNAP, G) \
    IGS(G, 0) IGS(G, 1) IGS(G, 2) IGS(G, 3) \
    IGS(G, 4) IGS(G, 5) IGS(G, 6) IGS(G, 7) \
    DO64(TRL, G) }

__global__ __launch_bounds__(64, 1) void k_inv(const float* Mws, float* Kws) {
    __shared__ float Msnap[512];
    const int b = blockIdx.x, t = threadIdx.x;  // lane t owns column t
    const int base = b * 4096;
    const int gl = t & 7;
    float a[64];
    DO64(GJ_LOAD, 0)
    MACRO_STEP(0) MACRO_STEP(1) MACRO_STEP(2) MACRO_STEP(3)
    MACRO_STEP(4) MACRO_STEP(5) MACRO_STEP(6) MACRO_STEP(7)
    DO64(GJ_STORE, 0)
}

// ---- k_post: Newton refinement + E. 8 blocks.
__global__ __launch_bounds__(256) void k_post(const float* coeff, const float* coeff_l,
                                              const float* Mws, const float* CPws,
                                              const float* Kws, float* Eout) {
    __shared__ float Ms[4096], CPs[4096], Ks[4096], Tds[4096], Tas[4096];
    const int b = blockIdx.x, t = threadIdx.x;
    const int tx = t & 15, ty = t >> 4;

    for (int idx = t; idx < 4096; idx += 256) {
        Ms[idx] = Mws[b * 4096 + idx];
        CPs[idx] = CPws[b * 4096 + idx];
        Ks[idx] = Kws[b * 4096 + idx];
    }
    __syncthreads();

    {
        const int i0 = ty * 4, j0 = tx * 4;
        float accd[4][4], acca[4][4];
#pragma unroll
        for (int i = 0; i < 4; ++i)
#pragma unroll
            for (int j = 0; j < 4; ++j) { accd[i][j] = 0.f; acca[i][j] = 0.f; }
        for (int q = 0; q < 64; ++q) {
            const float4 bv = *reinterpret_cast<const float4*>(&Ks[q * 64 + j0]);
            const float bb[4] = {bv.x, bv.y, bv.z, bv.w};
            float ad[4], aa[4];
#pragma unroll
            for (int i = 0; i < 4; ++i) {
                ad[i] = CPs[(i0 + i) * 64 + q];
                aa[i] = Ms[(i0 + i) * 64 + q];
            }
#pragma unroll
            for (int i = 0; i < 4; ++i)
#pragma unroll
                for (int j = 0; j < 4; ++j) {
                    accd[i][j] += ad[i] * bb[j];
                    acca[i][j] += aa[i] * bb[j];
                }
        }
#pragma unroll
        for (int i = 0; i < 4; ++i)
#pragma unroll
            for (int j = 0; j < 4; ++j) {
                Tds[(i0 + i) * 64 + j0 + j] = accd[i][j];
                Tas[(i0 + i) * 64 + j0 + j] = acca[i][j];
            }
    }
    __syncthreads();

    {
        const int e0 = ty * 4, c0 = tx * 4;
        float acc[4][4];
#pragma unroll
        for (int i = 0; i < 4; ++i)
#pragma unroll
            for (int j = 0; j < 4; ++j) acc[i][j] = 0.f;
        for (int q = 0; q < 64; ++q) {
            const float4 bv = *reinterpret_cast<const float4*>(&Tas[q * 64 + c0]);
            const float bb[4] = {bv.x, bv.y, bv.z, bv.w};
            float a[4];
#pragma unroll
            for (int i = 0; i < 4; ++i) a[i] = Tds[(e0 + i) * 64 + q];
#pragma unroll
            for (int i = 0; i < 4; ++i)
#pragma unroll
                for (int j = 0; j < 4; ++j) acc[i][j] += a[i] * bb[j];
        }
        float qv[4];
#pragma unroll
        for (int j = 0; j < 4; ++j) qv[j] = qval(coeff, coeff_l, b, c0 + j);
#pragma unroll
        for (int i = 0; i < 4; ++i) {
            float4 o;
            o.x = qv[0] * (2.f * Tds[(e0 + i) * 64 + c0 + 0] - acc[i][0]);
            o.y = qv[1] * (2.f * Tds[(e0 + i) * 64 + c0 + 1] - acc[i][1]);
            o.z = qv[2] * (2.f * Tds[(e0 + i) * 64 + c0 + 2] - acc[i][2]);
            o.w = qv[3] * (2.f * Tds[(e0 + i) * 64 + c0 + 3] - acc[i][3]);
            *reinterpret_cast<float4*>(&Eout[b * 4096 + (e0 + i) * 64 + (c0 ^ 16)]) = o;
        }
    }
}

// SE = S*E per batch, emitted in MFMA B-fragment layout (bf16 hi/lo).
// grid (hc=8, b=8)
__global__ __launch_bounds__(256) void k_se(const float* l, const float* r,
                                            const float* ll, const float* rl,
                                            const float* Ein, unsigned short* SEf) {
    __shared__ float Es[4096];
    __shared__ float Ss[64 * 66];
    __shared__ float SEs[64 * 65];
    const int b = blockIdx.y, hc = blockIdx.x, t = threadIdx.x;
    for (int idx = t; idx < 4096; idx += 256) {
        Es[idx] = Ein[b * 4096 + idx];
        const int hl_ = idx >> 6, e = idx & 63;
        Ss[hl_ * 66 + e] = Sval(l, r, ll, rl, hc * 64 + hl_, e);
    }
    __syncthreads();

    const int h = t >> 2;            // local row 0..63
    const int mg = (t & 3) * 16;
    float acc[16];
#pragma unroll
    for (int q = 0; q < 16; ++q) acc[q] = 0.f;
#pragma unroll 4
    for (int e = 0; e < 64; ++e) {
        const float s = Ss[h * 66 + e];
        const float* Er = Es + e * 64 + mg;
#pragma unroll
        for (int q = 0; q < 16; ++q) acc[q] += s * Er[q];
    }
#pragma unroll
    for (int q = 0; q < 16; ++q) SEs[h * 65 + mg + q] = acc[q];
    __syncthreads();

    unsigned short* outp = SEf + (size_t)b * 65536 + hc * 8192;
#pragma unroll
    for (int it = 0; it < 4; ++it) {
        const int widx0 = it * 2048 + t * 8;
        const int fl = widx0 >> 10;            // 0..7
        const int hl = (widx0 >> 9) & 1;
        const int lx = (widx0 >> 3) & 63;
        const int m = (fl & 3) * 16 + (lx & 15);
        const int hb = (fl >> 2) * 32 + ((lx >> 4) & 3) * 8;
        unsigned short wv[8];
#pragma unroll
        for (int i = 0; i < 8; ++i) {
            short hh, ss;
            bf16_split(SEs[(hb + i) * 65 + m], hh, ss);
            wv[i] = hl ? (unsigned short)ss : (unsigned short)hh;
        }
        uint4 pk;
        pk.x = (unsigned)wv[0] | ((unsigned)wv[1] << 16);
        pk.y = (unsigned)wv[2] | ((unsigned)wv[3] << 16);
        pk.z = (unsigned)wv[4] | ((unsigned)wv[5] << 16);
        pk.w = (unsigned)wv[6] | ((unsigned)wv[7] << 16);
        *reinterpret_cast<uint4*>(outp + widx0) = pk;
    }
}

// out = x + ((x * SE_b) * S^T) via split-bf16 MFMA, fragment-major B operands.
// 32-row tiles, grid (128,8), 4 waves (rw=row-half, cw=col-half).
// SOURCE-FORCED software pipeline: named register rings (x depth-4 for HBM
// latency, B-fragments depth-2 for L2). R11 evidence: compiler chose VGPR=32
// and serialized load->use (58us, all pipes <15%); the rings' liveness forces
// ~110 VGPR and 1-3 iterations of load-ahead.
#define LX(S, KK) { const int k0_ = (KK) * 32 + lk; \
    xa##S = *reinterpret_cast<const float4*>(xrow + k0_); \
    xc##S = *reinterpret_cast<const float4*>(xrow + k0_ + 4); }
#define LB(S, KK) { const int o0_ = ((KK) * 4 + 2 * cw) * 1024 + l * 8; \
    bh0##S = *reinterpret_cast<const bf16x8*>(sef + o0_); \
    bl0##S = *reinterpret_cast<const bf16x8*>(sef + o0_ + 512); \
    bh1##S = *reinterpret_cast<const bf16x8*>(sef + o0_ + 1024); \
    bl1##S = *reinterpret_cast<const bf16x8*>(sef + o0_ + 1536); }
#define C1(XS, BS) { \
    bf16x8 ah, al; \
    split8(xa##XS, xc##XS, ah, al); \
    ahh0 = __builtin_amdgcn_mfma_f32_16x16x32_bf16(ah, bh0##BS, ahh0, 0, 0, 0); \
    alh0 = __builtin_amdgcn_mfma_f32_16x16x32_bf16(al, bh0##BS, alh0, 0, 0, 0); \
    ahl0 = __builtin_amdgcn_mfma_f32_16x16x32_bf16(ah, bl0##BS, ahl0, 0, 0, 0); \
    ahh1 = __builtin_amdgcn_mfma_f32_16x16x32_bf16(ah, bh1##BS, ahh1, 0, 0, 0); \
    alh1 = __builtin_amdgcn_mfma_f32_16x16x32_bf16(al, bh1##BS, alh1, 0, 0, 0); \
    ahl1 = __builtin_amdgcn_mfma_f32_16x16x32_bf16(ah, bl1##BS, ahl1, 0, 0, 0); }

#define L2B(S, J2) { const int fb_ = (cw * 16 + (J2)) * 2048 + l * 8; \
    sh0##S = *reinterpret_cast<const bf16x8*>(Sf + fb_); \
    sl0##S = *reinterpret_cast<const bf16x8*>(Sf + fb_ + 512); \
    sh1##S = *reinterpret_cast<const bf16x8*>(Sf + fb_ + 1024); \
    sl1##S = *reinterpret_cast<const bf16x8*>(Sf + fb_ + 1536); }
#define L2X(S, J2) { const int h0_ = (cw * 16 + (J2)) * 16 + lm; \
    cx##S.x = xb[(size_t)(orow0 + 0) * F_ + h0_]; \
    cx##S.y = xb[(size_t)(orow0 + 1) * F_ + h0_]; \
    cx##S.z = xb[(size_t)(orow0 + 2) * F_ + h0_]; \
    cx##S.w = xb[(size_t)(orow0 + 3) * F_ + h0_]; }
#define C2(S, J2) { const int h0_ = (cw * 16 + (J2)) * 16 + lm; \
    f32x4 ca = {0.f, 0.f, 0.f, 0.f}; \
    f32x4 cb = {cx##S.x, cx##S.y, cx##S.z, cx##S.w}; \
    ca = __builtin_amdgcn_mfma_f32_16x16x32_bf16(zh0, sh0##S, ca, 0, 0, 0); \
    ca = __builtin_amdgcn_mfma_f32_16x16x32_bf16(zl0, sh0##S, ca, 0, 0, 0); \
    ca = __builtin_amdgcn_mfma_f32_16x16x32_bf16(zh0, sl0##S, ca, 0, 0, 0); \
    cb = __builtin_amdgcn_mfma_f32_16x16x32_bf16(zh1, sh1##S, cb, 0, 0, 0); \
    cb = __builtin_amdgcn_mfma_f32_16x16x32_bf16(zl1, sh1##S, cb, 0, 0, 0); \
    cb = __builtin_amdgcn_mfma_f32_16x16x32_bf16(zh1, sl1##S, cb, 0, 0, 0); \
    outb[(size_t)(orow0 + 0) * F_ + h0_] = ca[0] + cb[0]; \
    outb[(size_t)(orow0 + 1) * F_ + h0_] = ca[1] + cb[1]; \
    outb[(size_t)(orow0 + 2) * F_ + h0_] = ca[2] + cb[2]; \
    outb[(size_t)(orow0 + 3) * F_ + h0_] = ca[3] + cb[3]; }

__global__ __launch_bounds__(256, 2) void k_mix(const float* x,
                                                const unsigned short* SEf,
                                                const unsigned short* Sf,
                                                float* out) {
    __shared__ float Zs[32 * 68];
    const int b = blockIdx.y;
    const int r0 = blockIdx.x * 32;
    const int t = threadIdx.x;
    const int w = t >> 6;
    const int l = t & 63;
    const int lm = l & 15;
    const int lk = (l >> 4) * 8;
    const int rw = w & 1, cw = w >> 1;
    const float* xb = x + (size_t)b * N_ * F_;
    float* outb = out + (size_t)b * N_ * F_;
    const unsigned short* sef = SEf + (size_t)b * 65536;
    const float* xrow = xb + (size_t)(r0 + 16 * rw + lm) * F_;

    // ---- phase 1: Z[32][64] = X_tile * SE, pipelined ----
    f32x4 ahh0 = {0.f, 0.f, 0.f, 0.f}, alh0 = ahh0, ahl0 = ahh0;
    f32x4 ahh1 = ahh0, alh1 = ahh0, ahl1 = ahh0;
    float4 xaX0, xcX0, xaX1, xcX1, xaX2, xcX2, xaX3, xcX3;
    bf16x8 bh0A, bl0A, bh1A, bl1A, bh0B, bl0B, bh1B, bl1B;

    LX(X0, 0) LX(X1, 1) LX(X2, 2) LX(X3, 3) LB(A, 0) LB(B, 1)
    C1(X0, A) LX(X0, 4)  LB(A, 2)
    C1(X1, B) LX(X1, 5)  LB(B, 3)
    C1(X2, A) LX(X2, 6)  LB(A, 4)
    C1(X3, B) LX(X3, 7)  LB(B, 5)
    C1(X0, A) LX(X0, 8)  LB(A, 6)
    C1(X1, B) LX(X1, 9)  LB(B, 7)
    C1(X2, A) LX(X2, 10) LB(A, 8)
    C1(X3, B) LX(X3, 11) LB(B, 9)
    C1(X0, A) LX(X0, 12) LB(A, 10)
    C1(X1, B) LX(X1, 13) LB(B, 11)
    C1(X2, A) LX(X2, 14) LB(A, 12)
    C1(X3, B) LX(X3, 15) LB(B, 13)
    C1(X0, A) LB(A, 14)
    C1(X1, B) LB(B, 15)
    C1(X2, A)
    C1(X3, B)

#pragma unroll
    for (int r = 0; r < 4; ++r) {
        const int zr = (16 * rw + (l >> 4) * 4 + r) * 68 + 32 * cw;
        Zs[zr + lm] = ahh0[r] + alh0[r] + ahl0[r];
        Zs[zr + 16 + lm] = ahh1[r] + alh1[r] + ahl1[r];
    }
    __syncthreads();

    // ---- phase 2: out[32][512] = X + Z * S^T, pipelined ----
    bf16x8 zh0, zl0, zh1, zl1;
    {
        const float* zrow = &Zs[(16 * rw + lm) * 68];
        const float4 za = *reinterpret_cast<const float4*>(zrow + lk);
        const float4 zb = *reinterpret_cast<const float4*>(zrow + lk + 4);
        const float4 zc = *reinterpret_cast<const float4*>(zrow + 32 + lk);
        const float4 zd = *reinterpret_cast<const float4*>(zrow + 32 + lk + 4);
        split8(za, zb, zh0, zl0);
        split8(zc, zd, zh1, zl1);
    }
    const int orow0 = r0 + 16 * rw + (l >> 4) * 4;
    bf16x8 sh0A, sl0A, sh1A, sl1A, sh0B, sl0B, sh1B, sl1B;
    float4 cxA, cxB;

    L2B(A, 0) L2X(A, 0) L2B(B, 1) L2X(B, 1)
    C2(A, 0)  L2B(A, 2)  L2X(A, 2)
    C2(B, 1)  L2B(B, 3)  L2X(B, 3)
    C2(A, 2)  L2B(A, 4)  L2X(A, 4)
    C2(B, 3)  L2B(B, 5)  L2X(B, 5)
    C2(A, 4)  L2B(A, 6)  L2X(A, 6)
    C2(B, 5)  L2B(B, 7)  L2X(B, 7)
    C2(A, 6)  L2B(A, 8)  L2X(A, 8)
    C2(B, 7)  L2B(B, 9)  L2X(B, 9)
    C2(A, 8)  L2B(A, 10) L2X(A, 10)
    C2(B, 9)  L2B(B, 11) L2X(B, 11)
    C2(A, 10) L2B(A, 12) L2X(A, 12)
    C2(B, 11) L2B(B, 13) L2X(B, 13)
    C2(A, 12) L2B(A, 14) L2X(A, 14)
    C2(B, 13) L2B(B, 15) L2X(B, 15)
    C2(A, 14)
    C2(B, 15)
}

extern "C" void kernel_launch(void* const* d_in, const int* in_sizes, int n_in,
                              void* d_out, int out_size, void* d_ws, size_t ws_size,
                              hipStream_t stream) {
    (void)in_sizes; (void)n_in; (void)out_size; (void)ws_size;
    const float* x       = (const float*)d_in[0];
    const float* coeff   = (const float*)d_in[1];
    const float* gate    = (const float*)d_in[2];
    const float* coeff_l = (const float*)d_in[3];
    const float* gate_l  = (const float*)d_in[4];
    const float* comm    = (const float*)d_in[5];
    const float* l       = (const float*)d_in[6];
    const float* r       = (const float*)d_in[7];
    const float* ll      = (const float*)d_in[8];
    const float* rl      = (const float*)d_in[9];

    char* wsb = (char*)d_ws;
    float* GS   = (float*)(wsb);                              // 4096 f       @0
    float* E    = (float*)(wsb + 16384);                      // 8*4096 f     @16K
    unsigned short* SEf = (unsigned short*)(wsb + 147456);    // 8*65536 u16  @144K (1MB)
    unsigned short* Sf  = (unsigned short*)(wsb + 1196032);   // 65536 u16    @1168K (128K)
    float* Mws  = (float*)(wsb + 1327104);                    // 8*4096 f     @1296K
    float* CPws = (float*)(wsb + 1458176);                    // 8*4096 f     @1424K
    float* Kws  = (float*)(wsb + 1589248);                    // 8*4096 f     @1552K (ends 1680K)
    float* out = (float*)d_out;

    k_prep<<<dim3(64), dim3(256), 0, stream>>>(l, r, ll, rl, GS, Sf);
    k_pre<<<dim3(8), dim3(256), 0, stream>>>(coeff, gate, coeff_l, gate_l, comm, GS,
                                             Mws, CPws);
    k_inv<<<dim3(8), dim3(64), 0, stream>>>(Mws, Kws);
    k_post<<<dim3(8), dim3(256), 0, stream>>>(coeff, coeff_l, Mws, CPws, Kws, E);
    k_se<<<dim3(8, 8), dim3(256), 0, stream>>>(l, r, ll, rl, E, SEf);
    k_mix<<<dim3(128, 8), dim3(256), 0, stream>>>(x, SEf, Sf, out);
}

// Round 13
// 113.864 us; speedup vs baseline: 1.2858x; 1.0172x over previous
//
#include <hip/hip_runtime.h>

#define B_ 8
#define N_ 4096
#define F_ 512

typedef __attribute__((ext_vector_type(8))) short bf16x8;
typedef __attribute__((ext_vector_type(4))) float f32x4;

// S (512 x 64) = [left | right | left_local | right_local], each [512][16] row-major.
__device__ __forceinline__ float Sval(const float* l, const float* r,
                                      const float* ll, const float* rl,
                                      int h, int e) {
    const int m = e >> 4, c = e & 15;
    const float* p = (m == 0) ? l : (m == 1) ? r : (m == 2) ? ll : rl;
    return p[h * 16 + c];
}

__device__ __forceinline__ float qval(const float* coeff, const float* coeff_l,
                                      int b, int j) {
    if (j < 16) return 1.f;
    if (j < 32) return coeff[b * 16 + (j - 16)];
    if (j < 48) return 1.f;
    return coeff_l[b * 16 + (j - 48)];
}

__device__ __forceinline__ float lane_bcast(float v, int lane) {
    return __int_as_float(__builtin_amdgcn_readlane(__float_as_int(v), lane));
}

__device__ __forceinline__ unsigned short bf16_rn(float x) {
    unsigned u = __float_as_uint(x);
    unsigned r = u + 0x7FFFu + ((u >> 16) & 1u);
    return (unsigned short)(r >> 16);
}

// split x ~= hi + lo, both bf16 (error ~2^-17 |x|)
__device__ __forceinline__ void bf16_split(float x, short& hi, short& lo) {
    const unsigned short h = bf16_rn(x);
    const float hf = __uint_as_float(((unsigned)h) << 16);
    const unsigned short s = bf16_rn(x - hf);
    hi = (short)h; lo = (short)s;
}

__device__ __forceinline__ float b2f(unsigned short u) {
    return __uint_as_float(((unsigned)u) << 16);
}

// ---- k_prep: GS row i + S-fragment f2=i for phase-2 B-operand. grid 64.
__global__ __launch_bounds__(256) void k_prep(const float* l, const float* r,
                                              const float* ll, const float* rl,
                                              float* GS, unsigned short* Sf) {
    __shared__ float red[4][64];
    const int i = blockIdx.x;
    const int t = threadIdx.x;
    const int j = t & 63, seg = t >> 6;

    {
        const int ht = i >> 1, eh = i & 1;
        for (int idx = t; idx < 512; idx += 256) {
            const int lx = idx >> 3, ii = idx & 7;
            const int h = ht * 16 + (lx & 15);
            const int e = eh * 32 + ((lx >> 4) & 3) * 8 + ii;
            short hh, ss;
            bf16_split(Sval(l, r, ll, rl, h, e), hh, ss);
            Sf[(i * 2 + 0) * 512 + idx] = (unsigned short)hh;
            Sf[(i * 2 + 1) * 512 + idx] = (unsigned short)ss;
        }
    }

    float acc = 0.f;
    const int h0 = seg * 128;
    for (int h = h0; h < h0 + 128; ++h)
        acc += Sval(l, r, ll, rl, h, i) * Sval(l, r, ll, rl, h, j);
    red[seg][j] = acc;
    __syncthreads();
    if (t < 64) GS[i * 64 + t] = red[0][t] + red[1][t] + red[2][t] + red[3][t];
}

// ---- k_pre: build CP and M = I - 0.5 CQ^T GS CP -> Mws, CPws. 8 blocks.
__global__ __launch_bounds__(256) void k_pre(const float* coeff, const float* gate,
                                             const float* coeff_l, const float* gate_l,
                                             const float* comm, const float* GS,
                                             float* Mws, float* CPws) {
    __shared__ float GST[4096];
    __shared__ float CPs[4096];
    __shared__ float ABs[2048];
    __shared__ float u1s[32], u2s[32];

    const int b = blockIdx.x, t = threadIdx.x;
    const int tx = t & 15, ty = t >> 4;
    const float g = gate[b], gl = gate_l[b];
    const float cs = comm[b] / 12.0f;

    if (t < 32) {
        u1s[t] = (t < 16) ? g * coeff[b * 16 + t] : -g;
        u2s[t] = (t < 16) ? gl * coeff_l[b * 16 + t] : -gl;
    }
    for (int idx = t; idx < 4096; idx += 256) {
        const int i = idx & 63, e = idx >> 6;
        GST[idx] = -0.5f * qval(coeff, coeff_l, b, i) * GS[(i ^ 16) * 64 + e];
    }
    __syncthreads();

    for (int idx = t; idx < 2048; idx += 256) {
        const int which = idx >> 10;
        const int i = (idx >> 5) & 31, j = idx & 31;
        float val;
        if (which == 0) {
            const int v2i = (i < 16) ? 48 + i : 16 + i;
            const float v2sc = (i < 16) ? 1.f : coeff_l[b * 16 + (i - 16)];
            val = v2sc * u1s[j] * GS[v2i * 64 + j];
        } else {
            const int v1i = (i < 16) ? 16 + i : i - 16;
            const float v1sc = (i < 16) ? 1.f : coeff[b * 16 + (i - 16)];
            val = v1sc * u2s[j] * GS[v1i * 64 + 32 + j];
        }
        ABs[idx] = val;
    }
    __syncthreads();

    for (int idx = t; idx < 4096; idx += 256) {
        const int e = idx >> 6, j = idx & 63;
        float val = 0.f;
        if (j < 32) {
            if (e == j) val += 0.5f * u1s[j];
            if (e >= 32) val += cs * u2s[e - 32] * ABs[(e - 32) * 32 + j];
        } else {
            const int jp = j - 32;
            if (e == 32 + jp) val += 0.5f * u2s[jp];
            if (e < 32) val -= cs * u1s[e] * ABs[1024 + e * 32 + jp];
        }
        CPs[idx] = val;
        CPws[b * 4096 + idx] = val;
    }
    __syncthreads();

    {
        const int i0 = ty * 4, m0 = tx * 4;
        float acc[4][4];
#pragma unroll
        for (int i = 0; i < 4; ++i)
#pragma unroll
            for (int j = 0; j < 4; ++j) acc[i][j] = 0.f;
        for (int e = 0; e < 64; ++e) {
            const float4 av = *reinterpret_cast<const float4*>(&GST[e * 64 + i0]);
            const float4 bv = *reinterpret_cast<const float4*>(&CPs[e * 64 + m0]);
            const float a[4] = {av.x, av.y, av.z, av.w};
            const float bb[4] = {bv.x, bv.y, bv.z, bv.w};
#pragma unroll
            for (int i = 0; i < 4; ++i)
#pragma unroll
                for (int j = 0; j < 4; ++j) acc[i][j] += a[i] * bb[j];
        }
#pragma unroll
        for (int i = 0; i < 4; ++i) {
            float4 o;
            o.x = acc[i][0] + (((i0 + i) == (m0 + 0)) ? 1.f : 0.f);
            o.y = acc[i][1] + (((i0 + i) == (m0 + 1)) ? 1.f : 0.f);
            o.z = acc[i][2] + (((i0 + i) == (m0 + 2)) ? 1.f : 0.f);
            o.w = acc[i][3] + (((i0 + i) == (m0 + 3)) ? 1.f : 0.f);
            *reinterpret_cast<float4*>(&Mws[b * 4096 + (i0 + i) * 64 + m0]) = o;
        }
    }
}

// ---- k_inv: BLOCKED single-wave register Gauss-Jordan, 8 macro-steps, 0 barriers.
#define DO64(M, K) \
    M(0, K) M(1, K) M(2, K) M(3, K) M(4, K) M(5, K) M(6, K) M(7, K) \
    M(8, K) M(9, K) M(10, K) M(11, K) M(12, K) M(13, K) M(14, K) M(15, K) \
    M(16, K) M(17, K) M(18, K) M(19, K) M(20, K) M(21, K) M(22, K) M(23, K) \
    M(24, K) M(25, K) M(26, K) M(27, K) M(28, K) M(29, K) M(30, K) M(31, K) \
    M(32, K) M(33, K) M(34, K) M(35, K) M(36, K) M(37, K) M(38, K) M(39, K) \
    M(40, K) M(41, K) M(42, K) M(43, K) M(44, K) M(45, K) M(46, K) M(47, K) \
    M(48, K) M(49, K) M(50, K) M(51, K) M(52, K) M(53, K) M(54, K) M(55, K) \
    M(56, K) M(57, K) M(58, K) M(59, K) M(60, K) M(61, K) M(62, K) M(63, K)

#define GJ_LOAD(RR, K) a[RR] = Mws[base + (RR)*64 + t];
#define GJ_STORE(RR, K) Kws[base + (RR)*64 + t] = a[RR];

#define INV_SNAP(RR, G) if (ing) Msnap[(RR) * 8 + gl] = a[RR];

#define IGU(I, G, J) \
    if ((I) != (J)) { \
        const float f_ = lane_bcast(a[(G)*8 + (I)], (G)*8 + (J)); \
        a[(G)*8 + (I)] = __builtin_fmaf(-f_, akp[J], a[(G)*8 + (I)]); \
    }

#define IGS(G, J) { \
    const float dk = lane_bcast(a[(G)*8 + (J)], (G)*8 + (J)); \
    const float pinv = 1.0f / dk; \
    a[(G)*8 + (J)] = (t == ((G)*8 + (J))) ? pinv : a[(G)*8 + (J)] * pinv; \
    akp[J] = a[(G)*8 + (J)] + ((t == ((G)*8 + (J))) ? 1.0f : 0.0f); \
    IGU(0, G, J) IGU(1, G, J) IGU(2, G, J) IGU(3, G, J) \
    IGU(4, G, J) IGU(5, G, J) IGU(6, G, J) IGU(7, G, J) }

#define TRL(RR, G) \
    if (((RR) >> 3) != (G)) { \
        const float4 m0 = *reinterpret_cast<const float4*>(&Msnap[(RR) * 8]); \
        const float4 m1 = *reinterpret_cast<const float4*>(&Msnap[(RR) * 8 + 4]); \
        a[RR] = __builtin_fmaf(-m0.x, akp[0], a[RR]); \
        a[RR] = __builtin_fmaf(-m0.y, akp[1], a[RR]); \
        a[RR] = __builtin_fmaf(-m0.z, akp[2], a[RR]); \
        a[RR] = __builtin_fmaf(-m0.w, akp[3], a[RR]); \
        a[RR] = __builtin_fmaf(-m1.x, akp[4], a[RR]); \
        a[RR] = __builtin_fmaf(-m1.y, akp[5], a[RR]); \
        a[RR] = __builtin_fmaf(-m1.z, akp[6], a[RR]); \
        a[RR] = __builtin_fmaf(-m1.w, akp[7], a[RR]); \
    }

#define MACRO_STEP(G) { \
    float akp[8]; \
    const bool ing = ((t >> 3) == (G)); \
    DO64(INV_SNAP, G) \
    IGS(G, 0) IGS(G, 1) IGS(G, 2) IGS(G, 3) \
    IGS(G, 4) IGS(G, 5) IGS(G, 6) IGS(G, 7) \
    DO64(TRL, G) }

__global__ __launch_bounds__(64, 1) void k_inv(const float* Mws, float* Kws) {
    __shared__ float Msnap[512];
    const int b = blockIdx.x, t = threadIdx.x;  // lane t owns column t
    const int base = b * 4096;
    const int gl = t & 7;
    float a[64];
    DO64(GJ_LOAD, 0)
    MACRO_STEP(0) MACRO_STEP(1) MACRO_STEP(2) MACRO_STEP(3)
    MACRO_STEP(4) MACRO_STEP(5) MACRO_STEP(6) MACRO_STEP(7)
    DO64(GJ_STORE, 0)
}

// ---- k_post: Newton refinement + E. 8 blocks.
__global__ __launch_bounds__(256) void k_post(const float* coeff, const float* coeff_l,
                                              const float* Mws, const float* CPws,
                                              const float* Kws, float* Eout) {
    __shared__ float Ms[4096], CPs[4096], Ks[4096], Tds[4096], Tas[4096];
    const int b = blockIdx.x, t = threadIdx.x;
    const int tx = t & 15, ty = t >> 4;

    for (int idx = t; idx < 4096; idx += 256) {
        Ms[idx] = Mws[b * 4096 + idx];
        CPs[idx] = CPws[b * 4096 + idx];
        Ks[idx] = Kws[b * 4096 + idx];
    }
    __syncthreads();

    {
        const int i0 = ty * 4, j0 = tx * 4;
        float accd[4][4], acca[4][4];
#pragma unroll
        for (int i = 0; i < 4; ++i)
#pragma unroll
            for (int j = 0; j < 4; ++j) { accd[i][j] = 0.f; acca[i][j] = 0.f; }
        for (int q = 0; q < 64; ++q) {
            const float4 bv = *reinterpret_cast<const float4*>(&Ks[q * 64 + j0]);
            const float bb[4] = {bv.x, bv.y, bv.z, bv.w};
            float ad[4], aa[4];
#pragma unroll
            for (int i = 0; i < 4; ++i) {
                ad[i] = CPs[(i0 + i) * 64 + q];
                aa[i] = Ms[(i0 + i) * 64 + q];
            }
#pragma unroll
            for (int i = 0; i < 4; ++i)
#pragma unroll
                for (int j = 0; j < 4; ++j) {
                    accd[i][j] += ad[i] * bb[j];
                    acca[i][j] += aa[i] * bb[j];
                }
        }
#pragma unroll
        for (int i = 0; i < 4; ++i)
#pragma unroll
            for (int j = 0; j < 4; ++j) {
                Tds[(i0 + i) * 64 + j0 + j] = accd[i][j];
                Tas[(i0 + i) * 64 + j0 + j] = acca[i][j];
            }
    }
    __syncthreads();

    {
        const int e0 = ty * 4, c0 = tx * 4;
        float acc[4][4];
#pragma unroll
        for (int i = 0; i < 4; ++i)
#pragma unroll
            for (int j = 0; j < 4; ++j) acc[i][j] = 0.f;
        for (int q = 0; q < 64; ++q) {
            const float4 bv = *reinterpret_cast<const float4*>(&Tas[q * 64 + c0]);
            const float bb[4] = {bv.x, bv.y, bv.z, bv.w};
            float a[4];
#pragma unroll
            for (int i = 0; i < 4; ++i) a[i] = Tds[(e0 + i) * 64 + q];
#pragma unroll
            for (int i = 0; i < 4; ++i)
#pragma unroll
                for (int j = 0; j < 4; ++j) acc[i][j] += a[i] * bb[j];
        }
        float qv[4];
#pragma unroll
        for (int j = 0; j < 4; ++j) qv[j] = qval(coeff, coeff_l, b, c0 + j);
#pragma unroll
        for (int i = 0; i < 4; ++i) {
            float4 o;
            o.x = qv[0] * (2.f * Tds[(e0 + i) * 64 + c0 + 0] - acc[i][0]);
            o.y = qv[1] * (2.f * Tds[(e0 + i) * 64 + c0 + 1] - acc[i][1]);
            o.z = qv[2] * (2.f * Tds[(e0 + i) * 64 + c0 + 2] - acc[i][2]);
            o.w = qv[3] * (2.f * Tds[(e0 + i) * 64 + c0 + 3] - acc[i][3]);
            *reinterpret_cast<float4*>(&Eout[b * 4096 + (e0 + i) * 64 + (c0 ^ 16)]) = o;
        }
    }
}

// SE = S*E per batch, emitted in MFMA B-fragment layout (bf16 hi/lo).
// grid (hc=8, b=8)
__global__ __launch_bounds__(256) void k_se(const float* l, const float* r,
                                            const float* ll, const float* rl,
                                            const float* Ein, unsigned short* SEf) {
    __shared__ float Es[4096];
    __shared__ float Ss[64 * 66];
    __shared__ float SEs[64 * 65];
    const int b = blockIdx.y, hc = blockIdx.x, t = threadIdx.x;
    for (int idx = t; idx < 4096; idx += 256) {
        Es[idx] = Ein[b * 4096 + idx];
        const int hl_ = idx >> 6, e = idx & 63;
        Ss[hl_ * 66 + e] = Sval(l, r, ll, rl, hc * 64 + hl_, e);
    }
    __syncthreads();

    const int h = t >> 2;            // local row 0..63
    const int mg = (t & 3) * 16;
    float acc[16];
#pragma unroll
    for (int q = 0; q < 16; ++q) acc[q] = 0.f;
#pragma unroll 4
    for (int e = 0; e < 64; ++e) {
        const float s = Ss[h * 66 + e];
        const float* Er = Es + e * 64 + mg;
#pragma unroll
        for (int q = 0; q < 16; ++q) acc[q] += s * Er[q];
    }
#pragma unroll
    for (int q = 0; q < 16; ++q) SEs[h * 65 + mg + q] = acc[q];
    __syncthreads();

    unsigned short* outp = SEf + (size_t)b * 65536 + hc * 8192;
#pragma unroll
    for (int it = 0; it < 4; ++it) {
        const int widx0 = it * 2048 + t * 8;
        const int fl = widx0 >> 10;            // 0..7
        const int hl = (widx0 >> 9) & 1;
        const int lx = (widx0 >> 3) & 63;
        const int m = (fl & 3) * 16 + (lx & 15);
        const int hb = (fl >> 2) * 32 + ((lx >> 4) & 3) * 8;
        unsigned short wv[8];
#pragma unroll
        for (int i = 0; i < 8; ++i) {
            short hh, ss;
            bf16_split(SEs[(hb + i) * 65 + m], hh, ss);
            wv[i] = hl ? (unsigned short)ss : (unsigned short)hh;
        }
        uint4 pk;
        pk.x = (unsigned)wv[0] | ((unsigned)wv[1] << 16);
        pk.y = (unsigned)wv[2] | ((unsigned)wv[3] << 16);
        pk.z = (unsigned)wv[4] | ((unsigned)wv[5] << 16);
        pk.w = (unsigned)wv[6] | ((unsigned)wv[7] << 16);
        *reinterpret_cast<uint4*>(outp + widx0) = pk;
    }
}

// out = x + ((x * SE_b) * S^T) via split-bf16 MFMA.
// LDS-STAGED x (m97 pattern): the 32x512 x tile is loaded once per block,
// split into bf16 hi/lo LDS arrays [32][520] (pad 8 u16 -> <=4-way bank alias).
// Phase 1 A-fragments become single ds_read_b128 (no per-iter VALU split, no
// duplicate split across cw-waves); phase 2's residual x is reconstructed as
// hi+lo from LDS (adds ~2^-17|x| — same order as existing split error).
// R12 evidence: global-fed version latency-bound at 55us, all pipes <35%,
// VGPR pinned to 40 regardless of source-level pipelining.
// grid (128, 8), 4 waves (rw=row-half, cw=col-half), LDS 75264 B (2 blocks/CU).
__global__ __launch_bounds__(256, 2) void k_mix(const float* x,
                                                const unsigned short* SEf,
                                                const unsigned short* Sf,
                                                float* out) {
    __shared__ unsigned short xh[32 * 520];
    __shared__ unsigned short xl[32 * 520];
    __shared__ float Zs[32 * 68];
    const int b = blockIdx.y;
    const int r0 = blockIdx.x * 32;
    const int t = threadIdx.x;
    const int w = t >> 6;
    const int l = t & 63;
    const int lm = l & 15;
    const int lk = (l >> 4) * 8;
    const int rw = w & 1, cw = w >> 1;
    const float* xb = x + (size_t)b * N_ * F_;
    float* outb = out + (size_t)b * N_ * F_;
    const unsigned short* sef = SEf + (size_t)b * 65536;

    // ---- stage: x tile -> split bf16 hi/lo in LDS (coalesced 16B/lane reads) ----
#pragma unroll 4
    for (int it = 0; it < 16; ++it) {
        const int idx = it * 256 + t;
        const int row = idx >> 7, c4 = (idx & 127) * 4;
        const float4 v = *reinterpret_cast<const float4*>(
            xb + (size_t)(r0 + row) * F_ + c4);
        ushort4 hs, ls;
        short hh, ss;
        bf16_split(v.x, hh, ss); hs.x = (unsigned short)hh; ls.x = (unsigned short)ss;
        bf16_split(v.y, hh, ss); hs.y = (unsigned short)hh; ls.y = (unsigned short)ss;
        bf16_split(v.z, hh, ss); hs.z = (unsigned short)hh; ls.z = (unsigned short)ss;
        bf16_split(v.w, hh, ss); hs.w = (unsigned short)hh; ls.w = (unsigned short)ss;
        *reinterpret_cast<ushort4*>(&xh[row * 520 + c4]) = hs;
        *reinterpret_cast<ushort4*>(&xl[row * 520 + c4]) = ls;
    }
    __syncthreads();

    // ---- phase 1: Z[32][64] = X_tile * SE ; wave (rw,cw): rows 16rw.., Z-cols 32cw ----
    f32x4 ahh0 = {0.f, 0.f, 0.f, 0.f}, alh0 = ahh0, ahl0 = ahh0;
    f32x4 ahh1 = ahh0, alh1 = ahh0, ahl1 = ahh0;
    const unsigned short* xhr = xh + (16 * rw + lm) * 520;
    const unsigned short* xlr = xl + (16 * rw + lm) * 520;
#pragma unroll 4
    for (int kk = 0; kk < 16; ++kk) {
        const int k0 = kk * 32 + lk;
        const bf16x8 ah = *reinterpret_cast<const bf16x8*>(xhr + k0);
        const bf16x8 al = *reinterpret_cast<const bf16x8*>(xlr + k0);
        const int o0 = (kk * 4 + 2 * cw) * 1024 + l * 8;
        const bf16x8 bh0 = *reinterpret_cast<const bf16x8*>(sef + o0);
        const bf16x8 bl0 = *reinterpret_cast<const bf16x8*>(sef + o0 + 512);
        const bf16x8 bh1 = *reinterpret_cast<const bf16x8*>(sef + o0 + 1024);
        const bf16x8 bl1 = *reinterpret_cast<const bf16x8*>(sef + o0 + 1536);
        ahh0 = __builtin_amdgcn_mfma_f32_16x16x32_bf16(ah, bh0, ahh0, 0, 0, 0);
        alh0 = __builtin_amdgcn_mfma_f32_16x16x32_bf16(al, bh0, alh0, 0, 0, 0);
        ahl0 = __builtin_amdgcn_mfma_f32_16x16x32_bf16(ah, bl0, ahl0, 0, 0, 0);
        ahh1 = __builtin_amdgcn_mfma_f32_16x16x32_bf16(ah, bh1, ahh1, 0, 0, 0);
        alh1 = __builtin_amdgcn_mfma_f32_16x16x32_bf16(al, bh1, alh1, 0, 0, 0);
        ahl1 = __builtin_amdgcn_mfma_f32_16x16x32_bf16(ah, bl1, ahl1, 0, 0, 0);
    }
#pragma unroll
    for (int r = 0; r < 4; ++r) {
        const int zr = (16 * rw + (l >> 4) * 4 + r) * 68 + 32 * cw;
        Zs[zr + lm] = ahh0[r] + alh0[r] + ahl0[r];
        Zs[zr + 16 + lm] = ahh1[r] + alh1[r] + ahl1[r];
    }
    __syncthreads();

    // ---- phase 2: out[32][512] = X + Z * S^T ; wave: rows 16rw.., cols 256cw ----
    bf16x8 zh0, zl0, zh1, zl1;
    {
        const float* zrow = &Zs[(16 * rw + lm) * 68];
#pragma unroll
        for (int i = 0; i < 8; ++i) {
            short hh, ss;
            bf16_split(zrow[lk + i], hh, ss);
            zh0[i] = hh; zl0[i] = ss;
            bf16_split(zrow[32 + lk + i], hh, ss);
            zh1[i] = hh; zl1[i] = ss;
        }
    }
    const int lrow0 = 16 * rw + (l >> 4) * 4;   // local row of output fragment
    const int orow0 = r0 + lrow0;
#pragma unroll 2
    for (int j2 = 0; j2 < 16; ++j2) {
        const int ht = cw * 16 + j2;
        const int h0 = ht * 16 + lm;
        f32x4 ca = {0.f, 0.f, 0.f, 0.f};
        f32x4 cb;
#pragma unroll
        for (int r = 0; r < 4; ++r) {
            const int la = (lrow0 + r) * 520 + h0;
            cb[r] = b2f(xh[la]) + b2f(xl[la]);
        }
        const int fb = ht * 2048 + l * 8;
        const bf16x8 bh0 = *reinterpret_cast<const bf16x8*>(Sf + fb);
        const bf16x8 bl0 = *reinterpret_cast<const bf16x8*>(Sf + fb + 512);
        const bf16x8 bh1 = *reinterpret_cast<const bf16x8*>(Sf + fb + 1024);
        const bf16x8 bl1 = *reinterpret_cast<const bf16x8*>(Sf + fb + 1536);
        ca = __builtin_amdgcn_mfma_f32_16x16x32_bf16(zh0, bh0, ca, 0, 0, 0);
        ca = __builtin_amdgcn_mfma_f32_16x16x32_bf16(zl0, bh0, ca, 0, 0, 0);
        ca = __builtin_amdgcn_mfma_f32_16x16x32_bf16(zh0, bl0, ca, 0, 0, 0);
        cb = __builtin_amdgcn_mfma_f32_16x16x32_bf16(zh1, bh1, cb, 0, 0, 0);
        cb = __builtin_amdgcn_mfma_f32_16x16x32_bf16(zl1, bh1, cb, 0, 0, 0);
        cb = __builtin_amdgcn_mfma_f32_16x16x32_bf16(zh1, bl1, cb, 0, 0, 0);
#pragma unroll
        for (int r = 0; r < 4; ++r)
            outb[(size_t)(orow0 + r) * F_ + h0] = ca[r] + cb[r];
    }
}

extern "C" void kernel_launch(void* const* d_in, const int* in_sizes, int n_in,
                              void* d_out, int out_size, void* d_ws, size_t ws_size,
                              hipStream_t stream) {
    (void)in_sizes; (void)n_in; (void)out_size; (void)ws_size;
    const float* x       = (const float*)d_in[0];
    const float* coeff   = (const float*)d_in[1];
    const float* gate    = (const float*)d_in[2];
    const float* coeff_l = (const float*)d_in[3];
    const float* gate_l  = (const float*)d_in[4];
    const float* comm    = (const float*)d_in[5];
    const float* l       = (const float*)d_in[6];
    const float* r       = (const float*)d_in[7];
    const float* ll      = (const float*)d_in[8];
    const float* rl      = (const float*)d_in[9];

    char* wsb = (char*)d_ws;
    float* GS   = (float*)(wsb);                              // 4096 f       @0
    float* E    = (float*)(wsb + 16384);                      // 8*4096 f     @16K
    unsigned short* SEf = (unsigned short*)(wsb + 147456);    // 8*65536 u16  @144K (1MB)
    unsigned short* Sf  = (unsigned short*)(wsb + 1196032);   // 65536 u16    @1168K (128K)
    float* Mws  = (float*)(wsb + 1327104);                    // 8*4096 f     @1296K
    float* CPws = (float*)(wsb + 1458176);                    // 8*4096 f     @1424K
    float* Kws  = (float*)(wsb + 1589248);                    // 8*4096 f     @1552K (ends 1680K)
    float* out = (float*)d_out;

    k_prep<<<dim3(64), dim3(256), 0, stream>>>(l, r, ll, rl, GS, Sf);
    k_pre<<<dim3(8), dim3(256), 0, stream>>>(coeff, gate, coeff_l, gate_l, comm, GS,
                                             Mws, CPws);
    k_inv<<<dim3(8), dim3(64), 0, stream>>>(Mws, Kws);
    k_post<<<dim3(8), dim3(256), 0, stream>>>(coeff, coeff_l, Mws, CPws, Kws, E);
    k_se<<<dim3(8, 8), dim3(256), 0, stream>>>(l, r, ll, rl, E, SEf);
    k_mix<<<dim3(128, 8), dim3(256), 0, stream>>>(x, SEf, Sf, out);
}

// Round 14
// 112.254 us; speedup vs baseline: 1.3042x; 1.0143x over previous
//
#include <hip/hip_runtime.h>

#define B_ 8
#define N_ 4096
#define F_ 512

typedef __attribute__((ext_vector_type(8))) short bf16x8;
typedef __attribute__((ext_vector_type(4))) float f32x4;

#define XPAD 524   // u16 row stride: 262 dw == 6 mod 32 -> distinct lane banks; 8B-aligned

// S (512 x 64) = [left | right | left_local | right_local], each [512][16] row-major.
__device__ __forceinline__ float Sval(const float* l, const float* r,
                                      const float* ll, const float* rl,
                                      int h, int e) {
    const int m = e >> 4, c = e & 15;
    const float* p = (m == 0) ? l : (m == 1) ? r : (m == 2) ? ll : rl;
    return p[h * 16 + c];
}

__device__ __forceinline__ float qval(const float* coeff, const float* coeff_l,
                                      int b, int j) {
    if (j < 16) return 1.f;
    if (j < 32) return coeff[b * 16 + (j - 16)];
    if (j < 48) return 1.f;
    return coeff_l[b * 16 + (j - 48)];
}

__device__ __forceinline__ float lane_bcast(float v, int lane) {
    return __int_as_float(__builtin_amdgcn_readlane(__float_as_int(v), lane));
}

__device__ __forceinline__ unsigned short bf16_rn(float x) {
    unsigned u = __float_as_uint(x);
    unsigned r = u + 0x7FFFu + ((u >> 16) & 1u);
    return (unsigned short)(r >> 16);
}

// split x ~= hi + lo, both bf16 (error ~2^-17 |x|)
__device__ __forceinline__ void bf16_split(float x, short& hi, short& lo) {
    const unsigned short h = bf16_rn(x);
    const float hf = __uint_as_float(((unsigned)h) << 16);
    const unsigned short s = bf16_rn(x - hf);
    hi = (short)h; lo = (short)s;
}

__device__ __forceinline__ float b2f(unsigned short u) {
    return __uint_as_float(((unsigned)u) << 16);
}

// ---- k_prep: GS row i + S-fragment f2=i for phase-2 B-operand. grid 64.
__global__ __launch_bounds__(256) void k_prep(const float* l, const float* r,
                                              const float* ll, const float* rl,
                                              float* GS, unsigned short* Sf) {
    __shared__ float red[4][64];
    const int i = blockIdx.x;
    const int t = threadIdx.x;
    const int j = t & 63, seg = t >> 6;

    {
        const int ht = i >> 1, eh = i & 1;
        for (int idx = t; idx < 512; idx += 256) {
            const int lx = idx >> 3, ii = idx & 7;
            const int h = ht * 16 + (lx & 15);
            const int e = eh * 32 + ((lx >> 4) & 3) * 8 + ii;
            short hh, ss;
            bf16_split(Sval(l, r, ll, rl, h, e), hh, ss);
            Sf[(i * 2 + 0) * 512 + idx] = (unsigned short)hh;
            Sf[(i * 2 + 1) * 512 + idx] = (unsigned short)ss;
        }
    }

    float acc = 0.f;
    const int h0 = seg * 128;
    for (int h = h0; h < h0 + 128; ++h)
        acc += Sval(l, r, ll, rl, h, i) * Sval(l, r, ll, rl, h, j);
    red[seg][j] = acc;
    __syncthreads();
    if (t < 64) GS[i * 64 + t] = red[0][t] + red[1][t] + red[2][t] + red[3][t];
}

// ---- k_pre: build CP and M = I - 0.5 CQ^T GS CP -> Mws, CPws. 8 blocks.
__global__ __launch_bounds__(256) void k_pre(const float* coeff, const float* gate,
                                             const float* coeff_l, const float* gate_l,
                                             const float* comm, const float* GS,
                                             float* Mws, float* CPws) {
    __shared__ float GST[4096];
    __shared__ float CPs[4096];
    __shared__ float ABs[2048];
    __shared__ float u1s[32], u2s[32];

    const int b = blockIdx.x, t = threadIdx.x;
    const int tx = t & 15, ty = t >> 4;
    const float g = gate[b], gl = gate_l[b];
    const float cs = comm[b] / 12.0f;

    if (t < 32) {
        u1s[t] = (t < 16) ? g * coeff[b * 16 + t] : -g;
        u2s[t] = (t < 16) ? gl * coeff_l[b * 16 + t] : -gl;
    }
    for (int idx = t; idx < 4096; idx += 256) {
        const int i = idx & 63, e = idx >> 6;
        GST[idx] = -0.5f * qval(coeff, coeff_l, b, i) * GS[(i ^ 16) * 64 + e];
    }
    __syncthreads();

    for (int idx = t; idx < 2048; idx += 256) {
        const int which = idx >> 10;
        const int i = (idx >> 5) & 31, j = idx & 31;
        float val;
        if (which == 0) {
            const int v2i = (i < 16) ? 48 + i : 16 + i;
            const float v2sc = (i < 16) ? 1.f : coeff_l[b * 16 + (i - 16)];
            val = v2sc * u1s[j] * GS[v2i * 64 + j];
        } else {
            const int v1i = (i < 16) ? 16 + i : i - 16;
            const float v1sc = (i < 16) ? 1.f : coeff[b * 16 + (i - 16)];
            val = v1sc * u2s[j] * GS[v1i * 64 + 32 + j];
        }
        ABs[idx] = val;
    }
    __syncthreads();

    for (int idx = t; idx < 4096; idx += 256) {
        const int e = idx >> 6, j = idx & 63;
        float val = 0.f;
        if (j < 32) {
            if (e == j) val += 0.5f * u1s[j];
            if (e >= 32) val += cs * u2s[e - 32] * ABs[(e - 32) * 32 + j];
        } else {
            const int jp = j - 32;
            if (e == 32 + jp) val += 0.5f * u2s[jp];
            if (e < 32) val -= cs * u1s[e] * ABs[1024 + e * 32 + jp];
        }
        CPs[idx] = val;
        CPws[b * 4096 + idx] = val;
    }
    __syncthreads();

    {
        const int i0 = ty * 4, m0 = tx * 4;
        float acc[4][4];
#pragma unroll
        for (int i = 0; i < 4; ++i)
#pragma unroll
            for (int j = 0; j < 4; ++j) acc[i][j] = 0.f;
        for (int e = 0; e < 64; ++e) {
            const float4 av = *reinterpret_cast<const float4*>(&GST[e * 64 + i0]);
            const float4 bv = *reinterpret_cast<const float4*>(&CPs[e * 64 + m0]);
            const float a[4] = {av.x, av.y, av.z, av.w};
            const float bb[4] = {bv.x, bv.y, bv.z, bv.w};
#pragma unroll
            for (int i = 0; i < 4; ++i)
#pragma unroll
                for (int j = 0; j < 4; ++j) acc[i][j] += a[i] * bb[j];
        }
#pragma unroll
        for (int i = 0; i < 4; ++i) {
            float4 o;
            o.x = acc[i][0] + (((i0 + i) == (m0 + 0)) ? 1.f : 0.f);
            o.y = acc[i][1] + (((i0 + i) == (m0 + 1)) ? 1.f : 0.f);
            o.z = acc[i][2] + (((i0 + i) == (m0 + 2)) ? 1.f : 0.f);
            o.w = acc[i][3] + (((i0 + i) == (m0 + 3)) ? 1.f : 0.f);
            *reinterpret_cast<float4*>(&Mws[b * 4096 + (i0 + i) * 64 + m0]) = o;
        }
    }
}

// ---- k_inv: BLOCKED single-wave register Gauss-Jordan, 8 macro-steps, 0 barriers.
#define DO64(M, K) \
    M(0, K) M(1, K) M(2, K) M(3, K) M(4, K) M(5, K) M(6, K) M(7, K) \
    M(8, K) M(9, K) M(10, K) M(11, K) M(12, K) M(13, K) M(14, K) M(15, K) \
    M(16, K) M(17, K) M(18, K) M(19, K) M(20, K) M(21, K) M(22, K) M(23, K) \
    M(24, K) M(25, K) M(26, K) M(27, K) M(28, K) M(29, K) M(30, K) M(31, K) \
    M(32, K) M(33, K) M(34, K) M(35, K) M(36, K) M(37, K) M(38, K) M(39, K) \
    M(40, K) M(41, K) M(42, K) M(43, K) M(44, K) M(45, K) M(46, K) M(47, K) \
    M(48, K) M(49, K) M(50, K) M(51, K) M(52, K) M(53, K) M(54, K) M(55, K) \
    M(56, K) M(57, K) M(58, K) M(59, K) M(60, K) M(61, K) M(62, K) M(63, K)

#define GJ_LOAD(RR, K) a[RR] = Mws[base + (RR)*64 + t];
#define GJ_STORE(RR, K) Kws[base + (RR)*64 + t] = a[RR];

#define INV_SNAP(RR, G) if (ing) Msnap[(RR) * 8 + gl] = a[RR];

#define IGU(I, G, J) \
    if ((I) != (J)) { \
        const float f_ = lane_bcast(a[(G)*8 + (I)], (G)*8 + (J)); \
        a[(G)*8 + (I)] = __builtin_fmaf(-f_, akp[J], a[(G)*8 + (I)]); \
    }

#define IGS(G, J) { \
    const float dk = lane_bcast(a[(G)*8 + (J)], (G)*8 + (J)); \
    const float pinv = 1.0f / dk; \
    a[(G)*8 + (J)] = (t == ((G)*8 + (J))) ? pinv : a[(G)*8 + (J)] * pinv; \
    akp[J] = a[(G)*8 + (J)] + ((t == ((G)*8 + (J))) ? 1.0f : 0.0f); \
    IGU(0, G, J) IGU(1, G, J) IGU(2, G, J) IGU(3, G, J) \
    IGU(4, G, J) IGU(5, G, J) IGU(6, G, J) IGU(7, G, J) }

#define TRL(RR, G) \
    if (((RR) >> 3) != (G)) { \
        const float4 m0 = *reinterpret_cast<const float4*>(&Msnap[(RR) * 8]); \
        const float4 m1 = *reinterpret_cast<const float4*>(&Msnap[(RR) * 8 + 4]); \
        a[RR] = __builtin_fmaf(-m0.x, akp[0], a[RR]); \
        a[RR] = __builtin_fmaf(-m0.y, akp[1], a[RR]); \
        a[RR] = __builtin_fmaf(-m0.z, akp[2], a[RR]); \
        a[RR] = __builtin_fmaf(-m0.w, akp[3], a[RR]); \
        a[RR] = __builtin_fmaf(-m1.x, akp[4], a[RR]); \
        a[RR] = __builtin_fmaf(-m1.y, akp[5], a[RR]); \
        a[RR] = __builtin_fmaf(-m1.z, akp[6], a[RR]); \
        a[RR] = __builtin_fmaf(-m1.w, akp[7], a[RR]); \
    }

#define MACRO_STEP(G) { \
    float akp[8]; \
    const bool ing = ((t >> 3) == (G)); \
    DO64(INV_SNAP, G) \
    IGS(G, 0) IGS(G, 1) IGS(G, 2) IGS(G, 3) \
    IGS(G, 4) IGS(G, 5) IGS(G, 6) IGS(G, 7) \
    DO64(TRL, G) }

__global__ __launch_bounds__(64, 1) void k_inv(const float* Mws, float* Kws) {
    __shared__ float Msnap[512];
    const int b = blockIdx.x, t = threadIdx.x;  // lane t owns column t
    const int base = b * 4096;
    const int gl = t & 7;
    float a[64];
    DO64(GJ_LOAD, 0)
    MACRO_STEP(0) MACRO_STEP(1) MACRO_STEP(2) MACRO_STEP(3)
    MACRO_STEP(4) MACRO_STEP(5) MACRO_STEP(6) MACRO_STEP(7)
    DO64(GJ_STORE, 0)
}

// ---- k_sepost: fused Newton+E (per-b, redundantly per hc) and SE-chunk emission.
// grid (hc=8, b=8). LDS flat 80KB, phase-overlaid:
//  phase A: R0 Ms | R1 CPs | R2 Ks | R3 Tds | R4 Tas
//  phase B: E -> R0 (Ms dead) ; Ss (4224f) -> R1+ (CPs/Ks-head dead)
//  phase C: SEs (4160f) -> smem+8320 (Ks-tail/Tds-head dead)
__global__ __launch_bounds__(256) void k_sepost(const float* coeff, const float* coeff_l,
                                                const float* l, const float* r,
                                                const float* ll, const float* rl,
                                                const float* Mws, const float* CPws,
                                                const float* Kws, unsigned short* SEf) {
    __shared__ float smem[20480];
    float* Ms  = smem;
    float* CPs = smem + 4096;
    float* Ks  = smem + 8192;
    float* Tds = smem + 12288;
    float* Tas = smem + 16384;
    float* Es  = smem;          // phase B
    float* Ss  = smem + 4096;   // phase B, stride 66 (4224 floats)
    float* SEs = smem + 8320;   // phase C, stride 65 (4160 floats)

    const int b = blockIdx.y, hc = blockIdx.x, t = threadIdx.x;
    const int tx = t & 15, ty = t >> 4;

    for (int idx = t; idx < 4096; idx += 256) {
        Ms[idx] = Mws[b * 4096 + idx];
        CPs[idx] = CPws[b * 4096 + idx];
        Ks[idx] = Kws[b * 4096 + idx];
    }
    __syncthreads();

    // Td = CP*K ; Ta = M*K
    {
        const int i0 = ty * 4, j0 = tx * 4;
        float accd[4][4], acca[4][4];
#pragma unroll
        for (int i = 0; i < 4; ++i)
#pragma unroll
            for (int j = 0; j < 4; ++j) { accd[i][j] = 0.f; acca[i][j] = 0.f; }
        for (int q = 0; q < 64; ++q) {
            const float4 bv = *reinterpret_cast<const float4*>(&Ks[q * 64 + j0]);
            const float bb[4] = {bv.x, bv.y, bv.z, bv.w};
            float ad[4], aa[4];
#pragma unroll
            for (int i = 0; i < 4; ++i) {
                ad[i] = CPs[(i0 + i) * 64 + q];
                aa[i] = Ms[(i0 + i) * 64 + q];
            }
#pragma unroll
            for (int i = 0; i < 4; ++i)
#pragma unroll
                for (int j = 0; j < 4; ++j) {
                    accd[i][j] += ad[i] * bb[j];
                    acca[i][j] += aa[i] * bb[j];
                }
        }
        __syncthreads();  // everyone done reading Ms/CPs/Ks
#pragma unroll
        for (int i = 0; i < 4; ++i)
#pragma unroll
            for (int j = 0; j < 4; ++j) {
                Tds[(i0 + i) * 64 + j0 + j] = accd[i][j];
                Tas[(i0 + i) * 64 + j0 + j] = acca[i][j];
            }
    }
    __syncthreads();

    // E[e][c^16] = q(c)*(2Td - Td*Ta)[e][c] -> R0 ; Ss chunk -> R1+
    {
        const int e0 = ty * 4, c0 = tx * 4;
        float acc[4][4];
#pragma unroll
        for (int i = 0; i < 4; ++i)
#pragma unroll
            for (int j = 0; j < 4; ++j) acc[i][j] = 0.f;
        for (int q = 0; q < 64; ++q) {
            const float4 bv = *reinterpret_cast<const float4*>(&Tas[q * 64 + c0]);
            const float bb[4] = {bv.x, bv.y, bv.z, bv.w};
            float a[4];
#pragma unroll
            for (int i = 0; i < 4; ++i) a[i] = Tds[(e0 + i) * 64 + q];
#pragma unroll
            for (int i = 0; i < 4; ++i)
#pragma unroll
                for (int j = 0; j < 4; ++j) acc[i][j] += a[i] * bb[j];
        }
        float qv[4];
#pragma unroll
        for (int j = 0; j < 4; ++j) qv[j] = qval(coeff, coeff_l, b, c0 + j);
#pragma unroll
        for (int i = 0; i < 4; ++i) {
            float4 o;
            o.x = qv[0] * (2.f * Tds[(e0 + i) * 64 + c0 + 0] - acc[i][0]);
            o.y = qv[1] * (2.f * Tds[(e0 + i) * 64 + c0 + 1] - acc[i][1]);
            o.z = qv[2] * (2.f * Tds[(e0 + i) * 64 + c0 + 2] - acc[i][2]);
            o.w = qv[3] * (2.f * Tds[(e0 + i) * 64 + c0 + 3] - acc[i][3]);
            *reinterpret_cast<float4*>(&Es[(e0 + i) * 64 + (c0 ^ 16)]) = o;
        }
        for (int idx = t; idx < 4096; idx += 256) {
            const int hl_ = idx >> 6, e = idx & 63;
            Ss[hl_ * 66 + e] = Sval(l, r, ll, rl, hc * 64 + hl_, e);
        }
    }
    __syncthreads();

    // SE rows: SEs[h][m] = sum_e Ss[h][e]*Es[e][m]
    {
        const int h = t >> 2;
        const int mg = (t & 3) * 16;
        float acc[16];
#pragma unroll
        for (int q = 0; q < 16; ++q) acc[q] = 0.f;
#pragma unroll 4
        for (int e = 0; e < 64; ++e) {
            const float s = Ss[h * 66 + e];
            const float* Er = Es + e * 64 + mg;
#pragma unroll
            for (int q = 0; q < 16; ++q) acc[q] += s * Er[q];
        }
        __syncthreads();  // Tds-head about to be overwritten by SEs
#pragma unroll
        for (int q = 0; q < 16; ++q) SEs[h * 65 + mg + q] = acc[q];
    }
    __syncthreads();

    unsigned short* outp = SEf + (size_t)b * 65536 + hc * 8192;
#pragma unroll
    for (int it = 0; it < 4; ++it) {
        const int widx0 = it * 2048 + t * 8;
        const int fl = widx0 >> 10;            // 0..7
        const int hl = (widx0 >> 9) & 1;
        const int lx = (widx0 >> 3) & 63;
        const int m = (fl & 3) * 16 + (lx & 15);
        const int hb = (fl >> 2) * 32 + ((lx >> 4) & 3) * 8;
        unsigned short wv[8];
#pragma unroll
        for (int i = 0; i < 8; ++i) {
            short hh, ss;
            bf16_split(SEs[(hb + i) * 65 + m], hh, ss);
            wv[i] = hl ? (unsigned short)ss : (unsigned short)hh;
        }
        uint4 pk;
        pk.x = (unsigned)wv[0] | ((unsigned)wv[1] << 16);
        pk.y = (unsigned)wv[2] | ((unsigned)wv[3] << 16);
        pk.z = (unsigned)wv[4] | ((unsigned)wv[5] << 16);
        pk.w = (unsigned)wv[6] | ((unsigned)wv[7] << 16);
        *reinterpret_cast<uint4*>(outp + widx0) = pk;
    }
}

// out = x + ((x * SE_b) * S^T) via split-bf16 MFMA, LDS-staged x (hi/lo).
// Row stride XPAD=524 u16 (262 dw == 6 mod 32): the 520-stride version had
// 1.64M bank-conflict cycles (260 dw == 4 mod 32 -> 8 banks for 16 lanes) and
// 4B-misaligned ushort4 stores on odd rows. 524 -> distinct lane banks (~2-way,
// free per m136) and 8B-aligned rows.
// grid (128, 8), 4 waves (rw=row-half, cw=col-half).
__global__ __launch_bounds__(256, 2) void k_mix(const float* x,
                                                const unsigned short* SEf,
                                                const unsigned short* Sf,
                                                float* out) {
    __shared__ unsigned short xh[32 * XPAD];
    __shared__ unsigned short xl[32 * XPAD];
    __shared__ float Zs[32 * 68];
    const int b = blockIdx.y;
    const int r0 = blockIdx.x * 32;
    const int t = threadIdx.x;
    const int w = t >> 6;
    const int l = t & 63;
    const int lm = l & 15;
    const int lk = (l >> 4) * 8;
    const int rw = w & 1, cw = w >> 1;
    const float* xb = x + (size_t)b * N_ * F_;
    float* outb = out + (size_t)b * N_ * F_;
    const unsigned short* sef = SEf + (size_t)b * 65536;

    // ---- stage: x tile -> split bf16 hi/lo in LDS (coalesced 16B/lane reads) ----
#pragma unroll 4
    for (int it = 0; it < 16; ++it) {
        const int idx = it * 256 + t;
        const int row = idx >> 7, c4 = (idx & 127) * 4;
        const float4 v = *reinterpret_cast<const float4*>(
            xb + (size_t)(r0 + row) * F_ + c4);
        ushort4 hs, ls;
        short hh, ss;
        bf16_split(v.x, hh, ss); hs.x = (unsigned short)hh; ls.x = (unsigned short)ss;
        bf16_split(v.y, hh, ss); hs.y = (unsigned short)hh; ls.y = (unsigned short)ss;
        bf16_split(v.z, hh, ss); hs.z = (unsigned short)hh; ls.z = (unsigned short)ss;
        bf16_split(v.w, hh, ss); hs.w = (unsigned short)hh; ls.w = (unsigned short)ss;
        *reinterpret_cast<ushort4*>(&xh[row * XPAD + c4]) = hs;
        *reinterpret_cast<ushort4*>(&xl[row * XPAD + c4]) = ls;
    }
    __syncthreads();

    // ---- phase 1: Z[32][64] = X_tile * SE ----
    f32x4 ahh0 = {0.f, 0.f, 0.f, 0.f}, alh0 = ahh0, ahl0 = ahh0;
    f32x4 ahh1 = ahh0, alh1 = ahh0, ahl1 = ahh0;
    const unsigned short* xhr = xh + (16 * rw + lm) * XPAD;
    const unsigned short* xlr = xl + (16 * rw + lm) * XPAD;
#pragma unroll 4
    for (int kk = 0; kk < 16; ++kk) {
        const int k0 = kk * 32 + lk;
        const bf16x8 ah = *reinterpret_cast<const bf16x8*>(xhr + k0);
        const bf16x8 al = *reinterpret_cast<const bf16x8*>(xlr + k0);
        const int o0 = (kk * 4 + 2 * cw) * 1024 + l * 8;
        const bf16x8 bh0 = *reinterpret_cast<const bf16x8*>(sef + o0);
        const bf16x8 bl0 = *reinterpret_cast<const bf16x8*>(sef + o0 + 512);
        const bf16x8 bh1 = *reinterpret_cast<const bf16x8*>(sef + o0 + 1024);
        const bf16x8 bl1 = *reinterpret_cast<const bf16x8*>(sef + o0 + 1536);
        ahh0 = __builtin_amdgcn_mfma_f32_16x16x32_bf16(ah, bh0, ahh0, 0, 0, 0);
        alh0 = __builtin_amdgcn_mfma_f32_16x16x32_bf16(al, bh0, alh0, 0, 0, 0);
        ahl0 = __builtin_amdgcn_mfma_f32_16x16x32_bf16(ah, bl0, ahl0, 0, 0, 0);
        ahh1 = __builtin_amdgcn_mfma_f32_16x16x32_bf16(ah, bh1, ahh1, 0, 0, 0);
        alh1 = __builtin_amdgcn_mfma_f32_16x16x32_bf16(al, bh1, alh1, 0, 0, 0);
        ahl1 = __builtin_amdgcn_mfma_f32_16x16x32_bf16(ah, bl1, ahl1, 0, 0, 0);
    }
#pragma unroll
    for (int r = 0; r < 4; ++r) {
        const int zr = (16 * rw + (l >> 4) * 4 + r) * 68 + 32 * cw;
        Zs[zr + lm] = ahh0[r] + alh0[r] + ahl0[r];
        Zs[zr + 16 + lm] = ahh1[r] + alh1[r] + ahl1[r];
    }
    __syncthreads();

    // ---- phase 2: out[32][512] = X + Z * S^T ----
    bf16x8 zh0, zl0, zh1, zl1;
    {
        const float* zrow = &Zs[(16 * rw + lm) * 68];
#pragma unroll
        for (int i = 0; i < 8; ++i) {
            short hh, ss;
            bf16_split(zrow[lk + i], hh, ss);
            zh0[i] = hh; zl0[i] = ss;
            bf16_split(zrow[32 + lk + i], hh, ss);
            zh1[i] = hh; zl1[i] = ss;
        }
    }
    const int lrow0 = 16 * rw + (l >> 4) * 4;
    const int orow0 = r0 + lrow0;
#pragma unroll 2
    for (int j2 = 0; j2 < 16; ++j2) {
        const int ht = cw * 16 + j2;
        const int h0 = ht * 16 + lm;
        f32x4 ca = {0.f, 0.f, 0.f, 0.f};
        f32x4 cb;
#pragma unroll
        for (int r = 0; r < 4; ++r) {
            const int la = (lrow0 + r) * XPAD + h0;
            cb[r] = b2f(xh[la]) + b2f(xl[la]);
        }
        const int fb = ht * 2048 + l * 8;
        const bf16x8 bh0 = *reinterpret_cast<const bf16x8*>(Sf + fb);
        const bf16x8 bl0 = *reinterpret_cast<const bf16x8*>(Sf + fb + 512);
        const bf16x8 bh1 = *reinterpret_cast<const bf16x8*>(Sf + fb + 1024);
        const bf16x8 bl1 = *reinterpret_cast<const bf16x8*>(Sf + fb + 1536);
        ca = __builtin_amdgcn_mfma_f32_16x16x32_bf16(zh0, bh0, ca, 0, 0, 0);
        ca = __builtin_amdgcn_mfma_f32_16x16x32_bf16(zl0, bh0, ca, 0, 0, 0);
        ca = __builtin_amdgcn_mfma_f32_16x16x32_bf16(zh0, bl0, ca, 0, 0, 0);
        cb = __builtin_amdgcn_mfma_f32_16x16x32_bf16(zh1, bh1, cb, 0, 0, 0);
        cb = __builtin_amdgcn_mfma_f32_16x16x32_bf16(zl1, bh1, cb, 0, 0, 0);
        cb = __builtin_amdgcn_mfma_f32_16x16x32_bf16(zh1, bl1, cb, 0, 0, 0);
#pragma unroll
        for (int r = 0; r < 4; ++r)
            outb[(size_t)(orow0 + r) * F_ + h0] = ca[r] + cb[r];
    }
}

extern "C" void kernel_launch(void* const* d_in, const int* in_sizes, int n_in,
                              void* d_out, int out_size, void* d_ws, size_t ws_size,
                              hipStream_t stream) {
    (void)in_sizes; (void)n_in; (void)out_size; (void)ws_size;
    const float* x       = (const float*)d_in[0];
    const float* coeff   = (const float*)d_in[1];
    const float* gate    = (const float*)d_in[2];
    const float* coeff_l = (const float*)d_in[3];
    const float* gate_l  = (const float*)d_in[4];
    const float* comm    = (const float*)d_in[5];
    const float* l       = (const float*)d_in[6];
    const float* r       = (const float*)d_in[7];
    const float* ll      = (const float*)d_in[8];
    const float* rl      = (const float*)d_in[9];

    char* wsb = (char*)d_ws;
    float* GS   = (float*)(wsb);                              // 4096 f       @0
    unsigned short* SEf = (unsigned short*)(wsb + 147456);    // 8*65536 u16  @144K (1MB)
    unsigned short* Sf  = (unsigned short*)(wsb + 1196032);   // 65536 u16    @1168K (128K)
    float* Mws  = (float*)(wsb + 1327104);                    // 8*4096 f     @1296K
    float* CPws = (float*)(wsb + 1458176);                    // 8*4096 f     @1424K
    float* Kws  = (float*)(wsb + 1589248);                    // 8*4096 f     @1552K (ends 1680K)
    float* out = (float*)d_out;

    k_prep<<<dim3(64), dim3(256), 0, stream>>>(l, r, ll, rl, GS, Sf);
    k_pre<<<dim3(8), dim3(256), 0, stream>>>(coeff, gate, coeff_l, gate_l, comm, GS,
                                             Mws, CPws);
    k_inv<<<dim3(8), dim3(64), 0, stream>>>(Mws, Kws);
    k_sepost<<<dim3(8, 8), dim3(256), 0, stream>>>(coeff, coeff_l, l, r, ll, rl,
                                                   Mws, CPws, Kws, SEf);
    k_mix<<<dim3(128, 8), dim3(256), 0, stream>>>(x, SEf, Sf, out);
}